// Round 10
// baseline (232.703 us; speedup 1.0000x reference)
//
#include <hip/hip_runtime.h>
#include <hip/hip_bf16.h>
#include <stdint.h>

#define HD 64
#define NH 16
#define TT 2048
#define DD 1024

typedef uint16_t u16;
typedef __bf16 bf16_t;
typedef bf16_t bf16x8 __attribute__((ext_vector_type(8)));
typedef float f32x4 __attribute__((ext_vector_type(4)));

__device__ __forceinline__ u16 f2b(float f) {
    union { float f; uint32_t u; } v; v.f = f;
    uint32_t u = v.u;
    u += 0x7fff + ((u >> 16) & 1);   // RNE
    return (u16)(u >> 16);
}

__device__ __forceinline__ u16 b16(float f) {
    union { __bf16 h; u16 u; } c; c.h = (__bf16)f; return c.u;  // HW cvt (RNE)
}

__device__ __forceinline__ void gload16(const void* g, void* l) {
    __builtin_amdgcn_global_load_lds(
        (__attribute__((address_space(1))) void*)g,
        (__attribute__((address_space(3))) void*)l, 16, 0, 0);
}

// ---------------- converts ----------------

__global__ void f32_to_bf16_vec(const float* __restrict__ in, u16* __restrict__ out, int n4) {
    int i = blockIdx.x * 256 + threadIdx.x;
    if (i >= n4) return;
    float4 v = ((const float4*)in)[i];
    ushort4 r;
    r.x = f2b(v.x); r.y = f2b(v.y); r.z = f2b(v.z); r.w = f2b(v.w);
    ((ushort4*)out)[i] = r;
}

// out[c][r] = bf16(in[r][c]); R,C multiples of 32; block (32,8)
__global__ void transpose_f32_bf16(const float* __restrict__ in, u16* __restrict__ out, int R, int C) {
    __shared__ float tile[32][33];
    const int tx = threadIdx.x, ty = threadIdx.y;
    const int c0 = blockIdx.x * 32, r0 = blockIdx.y * 32;
#pragma unroll
    for (int j = 0; j < 32; j += 8)
        tile[ty + j][tx] = in[(size_t)(r0 + ty + j) * C + c0 + tx];
    __syncthreads();
#pragma unroll
    for (int j = 0; j < 32; j += 8)
        out[(size_t)(c0 + ty + j) * R + r0 + tx] = f2b(tile[tx][ty + j]);
}

// ---------------- GEMM C = A[M,K] * Bt[N,K]^T, bf16 in, f32 acc ----------------
// BM=256 x BN=128, BK=32, 512 thr (8 waves 4Mx2N, 64x64/wave).
// 3-slot LDS = 72 KB. Counted vmcnt(3) -> ONE barrier -> 8 ds_read ->
// STG(t+2) -> 16 MFMA (plateau structure, ~700 TF at this shape).
// q epilogue scale folds 1/sqrt(64) * log2(e) for exp2-domain softmax.

template<int MODE>
__global__ __launch_bounds__(512, 4)
void gemm9(const u16* __restrict__ A, const u16* __restrict__ Bt,
           int N, int K, int nwg,
           u16* __restrict__ oq, u16* __restrict__ ok, u16* __restrict__ ovT,
           float* __restrict__ of)
{
    __shared__ __align__(16) u16 As[3][256 * 32];   // 48 KiB
    __shared__ __align__(16) u16 Bs[3][128 * 32];   // 24 KiB
    const int tid = threadIdx.x;
    const int lane = tid & 63, l15 = lane & 15, g = lane >> 4;
    const int wid = tid >> 6, wm = wid >> 1, wn = wid & 1;

    // row-major-chunked XCD swizzle: sid walks cols fast, row panels slow
    const int gx = N >> 7;                       // col panels of 128
    const int cpx = nwg >> 3;
    const int sid = (blockIdx.x & 7) * cpx + (blockIdx.x >> 3);
    const long row0 = (long)(sid / gx) * 256;
    const long col0 = (long)(sid % gx) * 128;

    const u16* Ag = A + row0 * K;
    const u16* Bg = Bt + col0 * K;

    const f32x4 z4 = {0.f, 0.f, 0.f, 0.f};
    f32x4 acc[4][4];
#pragma unroll
    for (int i = 0; i < 4; i++)
#pragma unroll
        for (int n = 0; n < 4; n++) acc[i][n] = z4;

    const int swz = (l15 >> 1) & 3;   // read-side chunk XOR == (row>>1)&3

#define STG(t_, s_) do { const int ko = (t_) << 5;                                                 \
        { const int c = tid;       const int r_ = c >> 2;                                          \
          gload16(Ag + (size_t)r_ * K + ko + ((((c & 3) ^ ((r_ >> 1) & 3))) << 3), &As[s_][c << 3]); } \
        { const int c = tid + 512; const int r_ = c >> 2;                                          \
          gload16(Ag + (size_t)r_ * K + ko + ((((c & 3) ^ ((r_ >> 1) & 3))) << 3), &As[s_][c << 3]); } \
        { const int c = tid;       const int r_ = c >> 2;                                          \
          gload16(Bg + (size_t)r_ * K + ko + ((((c & 3) ^ ((r_ >> 1) & 3))) << 3), &Bs[s_][c << 3]); } \
    } while (0)

    const int NT = K >> 5;   // 32
    STG(0, 0);
    STG(1, 1);
    int sc = 0;
    for (int t = 0; t < NT; ++t) {
        if (t < NT - 1) asm volatile("s_waitcnt vmcnt(3)" ::: "memory");  // tile t landed; t+1 in flight
        else            asm volatile("s_waitcnt vmcnt(0)" ::: "memory");
        __builtin_amdgcn_s_barrier();     // all waves' tile-t chunks visible
        bf16x8 af[4], bfr[4];
#pragma unroll
        for (int m = 0; m < 4; m++)
            af[m]  = *(const bf16x8*)&As[sc][(wm * 64 + m * 16 + l15) * 32 + ((g ^ swz) << 3)];
#pragma unroll
        for (int n = 0; n < 4; n++)
            bfr[n] = *(const bf16x8*)&Bs[sc][(wn * 64 + n * 16 + l15) * 32 + ((g ^ swz) << 3)];
        const int sn = (sc == 0) ? 2 : sc - 1;         // slot (t+2)%3 (freed at last barrier)
        if (t + 2 < NT) STG(t + 2, sn);
        __builtin_amdgcn_s_setprio(1);
#pragma unroll
        for (int m = 0; m < 4; m++)
#pragma unroll
            for (int n = 0; n < 4; n++)
                acc[m][n] = __builtin_amdgcn_mfma_f32_16x16x32_bf16(af[m], bfr[n], acc[m][n], 0, 0, 0);
        __builtin_amdgcn_s_setprio(0);
        sc = (sc == 2) ? 0 : sc + 1;
    }
#undef STG

    if (MODE == 0) {
        const int which = (int)(col0 >> 10);
        const long b = row0 >> 11;
#pragma unroll
        for (int m = 0; m < 4; m++) {
            const long r = row0 + wm * 64 + m * 16 + g * 4;
            const long t = r & (TT - 1);
#pragma unroll
            for (int n = 0; n < 4; n++) {
                const long c = col0 + wn * 64 + n * 16 + l15;
                const int h  = (int)((c >> 6) & 15);
                const int hd = (int)(c & 63);
                if (which == 0) {
                    // q scaled by (1/8) * log2(e): softmax runs in exp2 domain
#pragma unroll
                    for (int e = 0; e < 4; e++)
                        oq[((b * NH + h) * TT + t + e) * HD + hd] = f2b(acc[m][n][e] * 0.18033688f);
                } else if (which == 1) {
#pragma unroll
                    for (int e = 0; e < 4; e++)
                        ok[((b * NH + h) * TT + t + e) * HD + hd] = f2b(acc[m][n][e]);
                } else {
                    ushort4 pk;
                    pk.x = f2b(acc[m][n][0]); pk.y = f2b(acc[m][n][1]);
                    pk.z = f2b(acc[m][n][2]); pk.w = f2b(acc[m][n][3]);
                    *(ushort4*)&ovT[((b * NH + h) * HD + hd) * TT + t] = pk;
                }
            }
        }
    } else {
#pragma unroll
        for (int m = 0; m < 4; m++) {
            const long r = row0 + wm * 64 + m * 16 + g * 4;
#pragma unroll
            for (int n = 0; n < 4; n++) {
                const long c = col0 + wn * 64 + n * 16 + l15;
#pragma unroll
                for (int e = 0; e < 4; e++)
                    of[(r + e) * (long)N + c] = acc[m][n][e];
            }
        }
    }
}

// ---------------- flash attention (barrier-free, direct-global K/V) ----------------
// Grid 1024: XCD k owns bh in [8k,8k+8) (K+V for 8 heads = 4 MB, L2-resident);
// heavy qt first within XCD. 256 thr = 4 INDEPENDENT waves (no barriers, no LDS
// staging): each wave loads its K/V MFMA fragments directly from global (L2-hit,
// 64B segments). Wave-local tile count (no causal lockstep). Softmax in exp2
// domain (q pre-scaled by log2e; exp2f = native v_exp_f32). P repacked through
// per-wave LDS as 8B granules, granule ^ l15 swizzle (proven).

__global__ __launch_bounds__(256, 3)
void attn_fwd(const u16* __restrict__ gq, const u16* __restrict__ gk,
              const u16* __restrict__ gvT, u16* __restrict__ o)
{
    __shared__ __align__(16) u16 Plds[4][32 * 64];   // per-wave [q][16 x 8B granules]

    const int tid = threadIdx.x;
    const int wv = tid >> 6, lane = tid & 63, l15 = lane & 15, g = lane >> 4;
    const int blk = blockIdx.x;
    const int j = blk >> 3;
    const int bh = (blk & 7) * 8 + (j & 7);      // XCD (blk&7) keeps bh group
    const int qt = 15 - (j >> 3);                // heavy tiles first within XCD
    const int qw0 = qt * 128 + wv * 32;

    const u16* qbase = gq + (size_t)bh * TT * HD;
    const u16* kbase = gk + (size_t)bh * TT * HD;
    const u16* vbase = gvT + (size_t)bh * HD * TT;

    const float NEG_INF = -__builtin_inff();
    const f32x4 z4 = {0.f, 0.f, 0.f, 0.f};

    bf16x8 qf[2][2];
#pragma unroll
    for (int qi = 0; qi < 2; qi++)
#pragma unroll
        for (int hs = 0; hs < 2; hs++)
            qf[qi][hs] = *(const bf16x8*)(qbase + (size_t)(qw0 + qi * 16 + l15) * HD + hs * 32 + g * 8);

    f32x4 o_acc[2][4];
    float m[2], ls[2];
#pragma unroll
    for (int qi = 0; qi < 2; qi++) {
#pragma unroll
        for (int n = 0; n < 4; n++) o_acc[qi][n] = z4;
        m[qi] = NEG_INF; ls[qi] = 0.f;
    }

    const int nkt = (qw0 + 31) / 64 + 1;         // wave-local causal tile count
    for (int kt = 0; kt < nkt; ++kt) {
        const int k0 = kt * 64;
        // ---- K fragments direct from global (L2): 8 x b128 ----
        bf16x8 kf0[4], kf1[4];
#pragma unroll
        for (int kb = 0; kb < 4; kb++) {
            const u16* kr = kbase + (size_t)(k0 + kb * 16 + l15) * HD + g * 8;
            kf0[kb] = *(const bf16x8*)(kr);
            kf1[kb] = *(const bf16x8*)(kr + 32);
        }
        // swapped QK^T: s2[qi][kb]: q = qw0+qi*16+l15, key = k0+kb*16+g*4+e
        f32x4 s2[2][4];
        __builtin_amdgcn_s_setprio(1);
#pragma unroll
        for (int kb = 0; kb < 4; kb++)
#pragma unroll
            for (int qi = 0; qi < 2; qi++) {
                f32x4 t0 = __builtin_amdgcn_mfma_f32_16x16x32_bf16(kf0[kb], qf[qi][0], z4, 0, 0, 0);
                s2[qi][kb] = __builtin_amdgcn_mfma_f32_16x16x32_bf16(kf1[kb], qf[qi][1], t0, 0, 0, 0);
            }
        __builtin_amdgcn_s_setprio(0);
        // ---- V fragments issued now; land during softmax ----
        bf16x8 vf0[4], vf1[4];
#pragma unroll
        for (int n = 0; n < 4; n++) {
            const u16* vr = vbase + (size_t)(n * 16 + l15) * TT + k0 + g * 8;
            vf0[n] = *(const bf16x8*)(vr);
            vf1[n] = *(const bf16x8*)(vr + 32);
        }
        if (k0 + 63 > qw0) {
#pragma unroll
            for (int qi = 0; qi < 2; qi++)
#pragma unroll
                for (int kb = 0; kb < 4; kb++)
#pragma unroll
                    for (int e = 0; e < 4; e++) {
                        const int kk = k0 + kb * 16 + g * 4 + e;
                        const int qq = qw0 + qi * 16 + l15;
                        if (kk > qq) s2[qi][kb][e] = NEG_INF;
                    }
        }
        // in-register online softmax, exp2 domain (q = l15 per lane)
#pragma unroll
        for (int qi = 0; qi < 2; qi++) {
            f32x4 mx = s2[qi][0];
#pragma unroll
            for (int kb = 1; kb < 4; kb++)
#pragma unroll
                for (int e = 0; e < 4; e++) mx[e] = fmaxf(mx[e], s2[qi][kb][e]);
            float pmax = fmaxf(fmaxf(mx[0], mx[1]), fmaxf(mx[2], mx[3]));
            pmax = fmaxf(pmax, __shfl_xor(pmax, 16));
            pmax = fmaxf(pmax, __shfl_xor(pmax, 32));
            float mn = m[qi];
            const int resc = !__all(pmax <= mn + 11.541560f);   // defer-max, 2^11.54 = e^8
            if (resc) {
                const float mold = mn;
                mn = fmaxf(mold, pmax);
                m[qi] = mn;
                const float sc = exp2f(mold - mn);
                ls[qi] *= sc;
#pragma unroll
                for (int e = 0; e < 4; e++) {
                    const float sce = __shfl(sc, (lane & 48) + (((lane >> 4) & 3) << 2) + e);
#pragma unroll
                    for (int n = 0; n < 4; n++) o_acc[qi][n][e] *= sce;
                }
            }
            const int prow = qi * 16 + l15;
            u16* pb = &Plds[wv][prow * 64];
            float rsum = 0.f;
#pragma unroll
            for (int kb = 0; kb < 4; kb++) {
                const float p0 = exp2f(s2[qi][kb][0] - mn);
                const float p1 = exp2f(s2[qi][kb][1] - mn);
                const float p2 = exp2f(s2[qi][kb][2] - mn);
                const float p3 = exp2f(s2[qi][kb][3] - mn);
                rsum += (p0 + p1) + (p2 + p3);
                ushort4 pk;
                pk.x = b16(p0); pk.y = b16(p1); pk.z = b16(p2); pk.w = b16(p3);
                *(ushort4*)&pb[(((kb << 2) + g) ^ l15) * 4] = pk;
            }
            rsum += __shfl_xor(rsum, 16);
            rsum += __shfl_xor(rsum, 32);
            ls[qi] += rsum;
        }
        asm volatile("s_waitcnt lgkmcnt(0)" ::: "memory");
        // ---- PV: A = P (row q=l15, keys g*8+j), B = V (regs) ----
        __builtin_amdgcn_s_setprio(1);
#pragma unroll
        for (int qi = 0; qi < 2; qi++) {
            const u16* pb = &Plds[wv][(qi * 16 + l15) * 64];
            {   // ks = 0
                const int G0 = ((g << 1)) ^ l15, G1 = ((g << 1) + 1) ^ l15;
                const uint2 ra = *(const uint2*)&pb[G0 * 4];
                const uint2 rb = *(const uint2*)&pb[G1 * 4];
                union { uint32_t w[4]; bf16x8 v; } pu;
                pu.w[0] = ra.x; pu.w[1] = ra.y; pu.w[2] = rb.x; pu.w[3] = rb.y;
#pragma unroll
                for (int n = 0; n < 4; n++)
                    o_acc[qi][n] = __builtin_amdgcn_mfma_f32_16x16x32_bf16(pu.v, vf0[n], o_acc[qi][n], 0, 0, 0);
            }
            {   // ks = 1
                const int G0 = (8 + (g << 1)) ^ l15, G1 = (8 + (g << 1) + 1) ^ l15;
                const uint2 ra = *(const uint2*)&pb[G0 * 4];
                const uint2 rb = *(const uint2*)&pb[G1 * 4];
                union { uint32_t w[4]; bf16x8 v; } pu;
                pu.w[0] = ra.x; pu.w[1] = ra.y; pu.w[2] = rb.x; pu.w[3] = rb.y;
#pragma unroll
                for (int n = 0; n < 4; n++)
                    o_acc[qi][n] = __builtin_amdgcn_mfma_f32_16x16x32_bf16(pu.v, vf1[n], o_acc[qi][n], 0, 0, 0);
            }
        }
        __builtin_amdgcn_s_setprio(0);
    }

    const int b = bh >> 4, h = bh & 15;
#pragma unroll
    for (int qi = 0; qi < 2; qi++) {
        const float linv = 1.f / ls[qi];
#pragma unroll
        for (int e = 0; e < 4; e++) {
            const float inv = __shfl(linv, (lane & 48) + (((lane >> 4) & 3) << 2) + e);
            const int t = qw0 + qi * 16 + g * 4 + e;
#pragma unroll
            for (int n = 0; n < 4; n++)
                o[((size_t)(b * TT + t)) * DD + h * HD + n * 16 + l15] = f2b(o_acc[qi][n][e] * inv);
        }
    }
}

// ---------------- launch ----------------

extern "C" void kernel_launch(void* const* d_in, const int* in_sizes, int n_in,
                              void* d_out, int out_size, void* d_ws, size_t ws_size,
                              hipStream_t stream)
{
    const float* x     = (const float*)d_in[0];
    const float* w_qkv = (const float*)d_in[1];
    const float* w_o   = (const float*)d_in[2];
    float* out = (float*)d_out;
    char* ws = (char*)d_ws;

    u16* xb    = (u16*)(ws);                 // 8192x1024        16 MB
    u16* wqkvT = (u16*)(ws + 16777216);      // 3072x1024         6 MB
    u16* woT   = (u16*)(ws + 23068672);      // 1024x1024         2 MB
    u16* wsq   = (u16*)(ws + 25165824);      // [B,H,T,64]       16 MB
    u16* wsk   = (u16*)(ws + 41943040);      // [B,H,T,64]       16 MB
    u16* wsvT  = (u16*)(ws + 58720256);      // [B,H,64,T]       16 MB
    u16* attno = (u16*)(ws + 75497472);      // [B*T, D]         16 MB

    f32_to_bf16_vec<<<8192, 256, 0, stream>>>(x, xb, 2097152);
    dim3 tb(32, 8);
    transpose_f32_bf16<<<dim3(96, 32), tb, 0, stream>>>(w_qkv, wqkvT, 1024, 3072);
    transpose_f32_bf16<<<dim3(32, 32), tb, 0, stream>>>(w_o,   woT,   1024, 1024);

    gemm9<0><<<768, 512, 0, stream>>>(xb, wqkvT, 3072, 1024, 768, wsq, wsk, wsvT, nullptr);
    attn_fwd<<<1024, 256, 0, stream>>>(wsq, wsk, wsvT, attno);
    gemm9<1><<<256, 512, 0, stream>>>(attno, woT, 1024, 1024, 256, nullptr, nullptr, nullptr, out);
}

// Round 11
// 194.997 us; speedup vs baseline: 1.1934x; 1.1934x over previous
//
#include <hip/hip_runtime.h>
#include <hip/hip_bf16.h>
#include <stdint.h>

#define HD 64
#define NH 16
#define TT 2048
#define DD 1024

typedef uint16_t u16;
typedef __bf16 bf16_t;
typedef bf16_t bf16x8 __attribute__((ext_vector_type(8)));
typedef float f32x4 __attribute__((ext_vector_type(4)));

__device__ __forceinline__ u16 f2b(float f) {
    union { float f; uint32_t u; } v; v.f = f;
    uint32_t u = v.u;
    u += 0x7fff + ((u >> 16) & 1);   // RNE
    return (u16)(u >> 16);
}

__device__ __forceinline__ u16 b16(float f) {
    union { __bf16 h; u16 u; } c; c.h = (__bf16)f; return c.u;  // HW cvt (RNE)
}

__device__ __forceinline__ void gload16(const void* g, void* l) {
    __builtin_amdgcn_global_load_lds(
        (__attribute__((address_space(1))) void*)g,
        (__attribute__((address_space(3))) void*)l, 16, 0, 0);
}

// ---------------- converts ----------------

__global__ void f32_to_bf16_vec(const float* __restrict__ in, u16* __restrict__ out, int n4) {
    int i = blockIdx.x * 256 + threadIdx.x;
    if (i >= n4) return;
    float4 v = ((const float4*)in)[i];
    ushort4 r;
    r.x = f2b(v.x); r.y = f2b(v.y); r.z = f2b(v.z); r.w = f2b(v.w);
    ((ushort4*)out)[i] = r;
}

// out[c][r] = bf16(in[r][c]); R,C multiples of 32; block (32,8)
__global__ void transpose_f32_bf16(const float* __restrict__ in, u16* __restrict__ out, int R, int C) {
    __shared__ float tile[32][33];
    const int tx = threadIdx.x, ty = threadIdx.y;
    const int c0 = blockIdx.x * 32, r0 = blockIdx.y * 32;
#pragma unroll
    for (int j = 0; j < 32; j += 8)
        tile[ty + j][tx] = in[(size_t)(r0 + ty + j) * C + c0 + tx];
    __syncthreads();
#pragma unroll
    for (int j = 0; j < 32; j += 8)
        out[(size_t)(c0 + ty + j) * R + r0 + tx] = f2b(tile[tx][ty + j]);
}

// ---------------- GEMM C = A[M,K] * Bt[N,K]^T, bf16 in, f32 acc ----------------
// BM=256 x BN=128, BK=32, 512 thr (8 waves 4Mx2N, 64x64/wave).
// 3-slot LDS = 72 KB. Counted vmcnt(3) -> ONE barrier -> 8 ds_read ->
// STG(t+2) -> 16 MFMA (plateau structure, ~700 TF at this shape).
// q epilogue scale folds 1/sqrt(64) * log2(e) for exp2-domain softmax.

template<int MODE>
__global__ __launch_bounds__(512, 4)
void gemm9(const u16* __restrict__ A, const u16* __restrict__ Bt,
           int N, int K, int nwg,
           u16* __restrict__ oq, u16* __restrict__ ok, u16* __restrict__ ovT,
           float* __restrict__ of)
{
    __shared__ __align__(16) u16 As[3][256 * 32];   // 48 KiB
    __shared__ __align__(16) u16 Bs[3][128 * 32];   // 24 KiB
    const int tid = threadIdx.x;
    const int lane = tid & 63, l15 = lane & 15, g = lane >> 4;
    const int wid = tid >> 6, wm = wid >> 1, wn = wid & 1;

    // row-major-chunked XCD swizzle: sid walks cols fast, row panels slow
    const int gx = N >> 7;                       // col panels of 128
    const int cpx = nwg >> 3;
    const int sid = (blockIdx.x & 7) * cpx + (blockIdx.x >> 3);
    const long row0 = (long)(sid / gx) * 256;
    const long col0 = (long)(sid % gx) * 128;

    const u16* Ag = A + row0 * K;
    const u16* Bg = Bt + col0 * K;

    const f32x4 z4 = {0.f, 0.f, 0.f, 0.f};
    f32x4 acc[4][4];
#pragma unroll
    for (int i = 0; i < 4; i++)
#pragma unroll
        for (int n = 0; n < 4; n++) acc[i][n] = z4;

    const int swz = (l15 >> 1) & 3;   // read-side chunk XOR == (row>>1)&3

#define STG(t_, s_) do { const int ko = (t_) << 5;                                                 \
        { const int c = tid;       const int r_ = c >> 2;                                          \
          gload16(Ag + (size_t)r_ * K + ko + ((((c & 3) ^ ((r_ >> 1) & 3))) << 3), &As[s_][c << 3]); } \
        { const int c = tid + 512; const int r_ = c >> 2;                                          \
          gload16(Ag + (size_t)r_ * K + ko + ((((c & 3) ^ ((r_ >> 1) & 3))) << 3), &As[s_][c << 3]); } \
        { const int c = tid;       const int r_ = c >> 2;                                          \
          gload16(Bg + (size_t)r_ * K + ko + ((((c & 3) ^ ((r_ >> 1) & 3))) << 3), &Bs[s_][c << 3]); } \
    } while (0)

    const int NT = K >> 5;   // 32
    STG(0, 0);
    STG(1, 1);
    int sc = 0;
    for (int t = 0; t < NT; ++t) {
        if (t < NT - 1) asm volatile("s_waitcnt vmcnt(3)" ::: "memory");  // tile t landed; t+1 in flight
        else            asm volatile("s_waitcnt vmcnt(0)" ::: "memory");
        __builtin_amdgcn_s_barrier();     // all waves' tile-t chunks visible
        bf16x8 af[4], bfr[4];
#pragma unroll
        for (int m = 0; m < 4; m++)
            af[m]  = *(const bf16x8*)&As[sc][(wm * 64 + m * 16 + l15) * 32 + ((g ^ swz) << 3)];
#pragma unroll
        for (int n = 0; n < 4; n++)
            bfr[n] = *(const bf16x8*)&Bs[sc][(wn * 64 + n * 16 + l15) * 32 + ((g ^ swz) << 3)];
        const int sn = (sc == 0) ? 2 : sc - 1;         // slot (t+2)%3 (freed at last barrier)
        if (t + 2 < NT) STG(t + 2, sn);
        __builtin_amdgcn_s_setprio(1);
#pragma unroll
        for (int m = 0; m < 4; m++)
#pragma unroll
            for (int n = 0; n < 4; n++)
                acc[m][n] = __builtin_amdgcn_mfma_f32_16x16x32_bf16(af[m], bfr[n], acc[m][n], 0, 0, 0);
        __builtin_amdgcn_s_setprio(0);
        sc = (sc == 2) ? 0 : sc + 1;
    }
#undef STG

    if (MODE == 0) {
        const int which = (int)(col0 >> 10);
        const long b = row0 >> 11;
#pragma unroll
        for (int m = 0; m < 4; m++) {
            const long r = row0 + wm * 64 + m * 16 + g * 4;
            const long t = r & (TT - 1);
#pragma unroll
            for (int n = 0; n < 4; n++) {
                const long c = col0 + wn * 64 + n * 16 + l15;
                const int h  = (int)((c >> 6) & 15);
                const int hd = (int)(c & 63);
                if (which == 0) {
                    // q scaled by (1/8) * log2(e): softmax runs in exp2 domain
#pragma unroll
                    for (int e = 0; e < 4; e++)
                        oq[((b * NH + h) * TT + t + e) * HD + hd] = f2b(acc[m][n][e] * 0.18033688f);
                } else if (which == 1) {
#pragma unroll
                    for (int e = 0; e < 4; e++)
                        ok[((b * NH + h) * TT + t + e) * HD + hd] = f2b(acc[m][n][e]);
                } else {
                    ushort4 pk;
                    pk.x = f2b(acc[m][n][0]); pk.y = f2b(acc[m][n][1]);
                    pk.z = f2b(acc[m][n][2]); pk.w = f2b(acc[m][n][3]);
                    *(ushort4*)&ovT[((b * NH + h) * HD + hd) * TT + t] = pk;
                }
            }
        }
    } else {
#pragma unroll
        for (int m = 0; m < 4; m++) {
            const long r = row0 + wm * 64 + m * 16 + g * 4;
#pragma unroll
            for (int n = 0; n < 4; n++) {
                const long c = col0 + wn * 64 + n * 16 + l15;
#pragma unroll
                for (int e = 0; e < 4; e++)
                    of[(r + e) * (long)N + c] = acc[m][n][e];
            }
        }
    }
}

// ---------------- flash attention (hybrid: K staged 3-slot / V direct) ----------------
// Grid 1024: XCD k owns bh in [8k,8k+8) (K+V 4 MB, L2-resident); heavy qt first.
// 256 thr = 4 waves x 32 q. K tiles (64 keys) DMA-staged into a 3-slot LDS ring:
// ONE barrier + counted vmcnt(2) per tile (tile t+2 issued after barrier t into
// the slot all waves finished reading at t-1 -- same race-free argument as gemm9).
// V fragments load direct from global (L2-hit), issued BEFORE the K-DMA so the
// compiler's pre-PV wait is vmcnt(2), leaving the K pipeline in flight; consumed
// ~400cy later after softmax. Softmax in exp2 domain (q pre-scaled by log2e/8).
// P repacked through per-wave LDS as 8B granules, granule ^ l15 swizzle.

__global__ __launch_bounds__(256, 3)
void attn_fwd(const u16* __restrict__ gq, const u16* __restrict__ gk,
              const u16* __restrict__ gvT, u16* __restrict__ o)
{
    __shared__ __align__(16) u16 Klds[3][64 * 64];   // 24 KB, [key][hd] swizzled
    __shared__ __align__(16) u16 Plds[4][32 * 64];   // 16 KB, per-wave [q][granules]

    const int tid = threadIdx.x;
    const int wv = tid >> 6, lane = tid & 63, l15 = lane & 15, g = lane >> 4;
    const int blk = blockIdx.x;
    const int j = blk >> 3;
    const int bh = (blk & 7) * 8 + (j & 7);      // XCD (blk&7) keeps bh group
    const int qt = 15 - (j >> 3);                // heavy tiles first within XCD
    const int q0 = qt * 128;
    const int qw0 = q0 + wv * 32;

    const u16* qbase = gq + (size_t)bh * TT * HD;
    const u16* kbase = gk + (size_t)bh * TT * HD;
    const u16* vbase = gvT + (size_t)bh * HD * TT;

    const float NEG_INF = -__builtin_inff();
    const f32x4 z4 = {0.f, 0.f, 0.f, 0.f};

    bf16x8 qf[2][2];
#pragma unroll
    for (int qi = 0; qi < 2; qi++)
#pragma unroll
        for (int hs = 0; hs < 2; hs++)
            qf[qi][hs] = *(const bf16x8*)(qbase + (size_t)(qw0 + qi * 16 + l15) * HD + hs * 32 + g * 8);

    f32x4 o_acc[2][4];
    float m[2], ls[2];
#pragma unroll
    for (int qi = 0; qi < 2; qi++) {
#pragma unroll
        for (int n = 0; n < 4; n++) o_acc[qi][n] = z4;
        m[qi] = NEG_INF; ls[qi] = 0.f;
    }

    // K staging roles: 2 chunks/thread/tile (64 rows x 8 chunks = 512)
    const int r0_ = tid >> 3, c0_ = tid & 7;
    const int r1_ = (tid + 256) >> 3, c1_ = (tid + 256) & 7;

#define STGK(s_, k0s) do {                                                                                   \
        gload16(kbase + (size_t)((k0s) + r0_) * HD + ((c0_ ^ (r0_ & 7)) * 8), &Klds[s_][tid * 8]);           \
        gload16(kbase + (size_t)((k0s) + r1_) * HD + ((c1_ ^ (r1_ & 7)) * 8), &Klds[s_][(tid + 256) * 8]);   \
    } while (0)

    const int nkt = q0 / 64 + 2;
    STGK(0, 0);
    STGK(1, 64);
    int sc = 0;
    for (int kt = 0; kt < nkt; ++kt) {
        const int k0 = kt * 64;
        if (kt + 1 < nkt) asm volatile("s_waitcnt vmcnt(2)" ::: "memory");  // tile kt landed; kt+1 in flight
        else              asm volatile("s_waitcnt vmcnt(0)" ::: "memory");
        __builtin_amdgcn_s_barrier();
        const int act = (k0 <= qw0 + 31);
        // V direct-global, issued early (before K-DMA so PV's wait leaves DMA in flight)
        bf16x8 vf0[4], vf1[4];
        if (act) {
#pragma unroll
            for (int n = 0; n < 4; n++) {
                const u16* vr = vbase + (size_t)(n * 16 + l15) * TT + k0 + g * 8;
                vf0[n] = *(const bf16x8*)(vr);
                vf1[n] = *(const bf16x8*)(vr + 32);
            }
        }
        const int sn = (sc == 0) ? 2 : sc - 1;   // slot (kt+2)%3 (freed: all waves read it at kt-1)
        if (kt + 2 < nkt) STGK(sn, k0 + 128);
        if (act) {
            const int sw = l15 & 7;
            // swapped QK^T: s2[qi][kb]: q = qw0+qi*16+l15, key = k0+kb*16+g*4+e
            f32x4 s2[2][4];
            __builtin_amdgcn_s_setprio(1);
#pragma unroll
            for (int kb = 0; kb < 4; kb++) {
                bf16x8 kf0 = *(const bf16x8*)&Klds[sc][(kb * 16 + l15) * 64 + ((g ^ sw) * 8)];
                bf16x8 kf1 = *(const bf16x8*)&Klds[sc][(kb * 16 + l15) * 64 + (((4 + g) ^ sw) * 8)];
#pragma unroll
                for (int qi = 0; qi < 2; qi++) {
                    f32x4 t0 = __builtin_amdgcn_mfma_f32_16x16x32_bf16(kf0, qf[qi][0], z4, 0, 0, 0);
                    s2[qi][kb] = __builtin_amdgcn_mfma_f32_16x16x32_bf16(kf1, qf[qi][1], t0, 0, 0, 0);
                }
            }
            __builtin_amdgcn_s_setprio(0);
            if (k0 + 63 > qw0) {
#pragma unroll
                for (int qi = 0; qi < 2; qi++)
#pragma unroll
                    for (int kb = 0; kb < 4; kb++)
#pragma unroll
                        for (int e = 0; e < 4; e++) {
                            const int kk = k0 + kb * 16 + g * 4 + e;
                            const int qq = qw0 + qi * 16 + l15;
                            if (kk > qq) s2[qi][kb][e] = NEG_INF;
                        }
            }
            // in-register online softmax, exp2 domain (q = l15 per lane)
#pragma unroll
            for (int qi = 0; qi < 2; qi++) {
                f32x4 mx = s2[qi][0];
#pragma unroll
                for (int kb = 1; kb < 4; kb++)
#pragma unroll
                    for (int e = 0; e < 4; e++) mx[e] = fmaxf(mx[e], s2[qi][kb][e]);
                float pmax = fmaxf(fmaxf(mx[0], mx[1]), fmaxf(mx[2], mx[3]));
                pmax = fmaxf(pmax, __shfl_xor(pmax, 16));
                pmax = fmaxf(pmax, __shfl_xor(pmax, 32));
                float mn = m[qi];
                const int resc = !__all(pmax <= mn + 11.541560f);   // defer-max (2^11.54 = e^8)
                if (resc) {
                    const float mold = mn;
                    mn = fmaxf(mold, pmax);
                    m[qi] = mn;
                    const float sc2 = exp2f(mold - mn);
                    ls[qi] *= sc2;
#pragma unroll
                    for (int e = 0; e < 4; e++) {
                        const float sce = __shfl(sc2, (lane & 48) + (((lane >> 4) & 3) << 2) + e);
#pragma unroll
                        for (int n = 0; n < 4; n++) o_acc[qi][n][e] *= sce;
                    }
                }
                const int prow = qi * 16 + l15;
                u16* pb = &Plds[wv][prow * 64];
                float rsum = 0.f;
#pragma unroll
                for (int kb = 0; kb < 4; kb++) {
                    const float p0 = exp2f(s2[qi][kb][0] - mn);
                    const float p1 = exp2f(s2[qi][kb][1] - mn);
                    const float p2 = exp2f(s2[qi][kb][2] - mn);
                    const float p3 = exp2f(s2[qi][kb][3] - mn);
                    rsum += (p0 + p1) + (p2 + p3);
                    ushort4 pk;
                    pk.x = b16(p0); pk.y = b16(p1); pk.z = b16(p2); pk.w = b16(p3);
                    *(ushort4*)&pb[(((kb << 2) + g) ^ l15) * 4] = pk;
                }
                rsum += __shfl_xor(rsum, 16);
                rsum += __shfl_xor(rsum, 32);
                ls[qi] += rsum;
            }
            asm volatile("s_waitcnt lgkmcnt(0)" ::: "memory");
            // PV: A = P (row q=l15, keys g*8+j), B = V (regs)
            __builtin_amdgcn_s_setprio(1);
#pragma unroll
            for (int qi = 0; qi < 2; qi++) {
                const u16* pb = &Plds[wv][(qi * 16 + l15) * 64];
                {   // ks = 0
                    const int G0 = ((g << 1)) ^ l15, G1 = ((g << 1) + 1) ^ l15;
                    const uint2 ra = *(const uint2*)&pb[G0 * 4];
                    const uint2 rb = *(const uint2*)&pb[G1 * 4];
                    union { uint32_t w[4]; bf16x8 v; } pu;
                    pu.w[0] = ra.x; pu.w[1] = ra.y; pu.w[2] = rb.x; pu.w[3] = rb.y;
#pragma unroll
                    for (int n = 0; n < 4; n++)
                        o_acc[qi][n] = __builtin_amdgcn_mfma_f32_16x16x32_bf16(pu.v, vf0[n], o_acc[qi][n], 0, 0, 0);
                }
                {   // ks = 1
                    const int G0 = (8 + (g << 1)) ^ l15, G1 = (8 + (g << 1) + 1) ^ l15;
                    const uint2 ra = *(const uint2*)&pb[G0 * 4];
                    const uint2 rb = *(const uint2*)&pb[G1 * 4];
                    union { uint32_t w[4]; bf16x8 v; } pu;
                    pu.w[0] = ra.x; pu.w[1] = ra.y; pu.w[2] = rb.x; pu.w[3] = rb.y;
#pragma unroll
                    for (int n = 0; n < 4; n++)
                        o_acc[qi][n] = __builtin_amdgcn_mfma_f32_16x16x32_bf16(pu.v, vf1[n], o_acc[qi][n], 0, 0, 0);
                }
            }
            __builtin_amdgcn_s_setprio(0);
        }
        sc = (sc == 2) ? 0 : sc + 1;
    }
#undef STGK

    const int b = bh >> 4, h = bh & 15;
#pragma unroll
    for (int qi = 0; qi < 2; qi++) {
        const float linv = 1.f / ls[qi];
#pragma unroll
        for (int e = 0; e < 4; e++) {
            const float inv = __shfl(linv, (lane & 48) + (((lane >> 4) & 3) << 2) + e);
            const int t = qw0 + qi * 16 + g * 4 + e;
#pragma unroll
            for (int n = 0; n < 4; n++)
                o[((size_t)(b * TT + t)) * DD + h * HD + n * 16 + l15] = b16(o_acc[qi][n][e] * inv);
        }
    }
}

// ---------------- launch ----------------

extern "C" void kernel_launch(void* const* d_in, const int* in_sizes, int n_in,
                              void* d_out, int out_size, void* d_ws, size_t ws_size,
                              hipStream_t stream)
{
    const float* x     = (const float*)d_in[0];
    const float* w_qkv = (const float*)d_in[1];
    const float* w_o   = (const float*)d_in[2];
    float* out = (float*)d_out;
    char* ws = (char*)d_ws;

    u16* xb    = (u16*)(ws);                 // 8192x1024        16 MB
    u16* wqkvT = (u16*)(ws + 16777216);      // 3072x1024         6 MB
    u16* woT   = (u16*)(ws + 23068672);      // 1024x1024         2 MB
    u16* wsq   = (u16*)(ws + 25165824);      // [B,H,T,64]       16 MB
    u16* wsk   = (u16*)(ws + 41943040);      // [B,H,T,64]       16 MB
    u16* wsvT  = (u16*)(ws + 58720256);      // [B,H,64,T]       16 MB
    u16* attno = (u16*)(ws + 75497472);      // [B*T, D]         16 MB

    f32_to_bf16_vec<<<8192, 256, 0, stream>>>(x, xb, 2097152);
    dim3 tb(32, 8);
    transpose_f32_bf16<<<dim3(96, 32), tb, 0, stream>>>(w_qkv, wqkvT, 1024, 3072);
    transpose_f32_bf16<<<dim3(32, 32), tb, 0, stream>>>(w_o,   woT,   1024, 1024);

    gemm9<0><<<768, 512, 0, stream>>>(xb, wqkvT, 3072, 1024, 768, wsq, wsk, wsvT, nullptr);
    attn_fwd<<<1024, 256, 0, stream>>>(wsq, wsk, wsvT, attno);
    gemm9<1><<<256, 512, 0, stream>>>(attno, woT, 1024, 1024, 256, nullptr, nullptr, nullptr, out);
}

// Round 12
// 170.972 us; speedup vs baseline: 1.3611x; 1.1405x over previous
//
#include <hip/hip_runtime.h>
#include <hip/hip_bf16.h>
#include <stdint.h>

#define HD 64
#define NH 16
#define TT 2048
#define DD 1024

typedef uint16_t u16;
typedef __bf16 bf16_t;
typedef bf16_t bf16x8 __attribute__((ext_vector_type(8)));
typedef float f32x4 __attribute__((ext_vector_type(4)));

__device__ __forceinline__ u16 f2b(float f) {
    union { float f; uint32_t u; } v; v.f = f;
    uint32_t u = v.u;
    u += 0x7fff + ((u >> 16) & 1);   // RNE
    return (u16)(u >> 16);
}

__device__ __forceinline__ u16 b16(float f) {
    union { __bf16 h; u16 u; } c; c.h = (__bf16)f; return c.u;  // HW cvt (RNE)
}

__device__ __forceinline__ void gload16(const void* g, void* l) {
    __builtin_amdgcn_global_load_lds(
        (__attribute__((address_space(1))) void*)g,
        (__attribute__((address_space(3))) void*)l, 16, 0, 0);
}

// ---------------- converts ----------------

__global__ void f32_to_bf16_vec(const float* __restrict__ in, u16* __restrict__ out, int n4) {
    int i = blockIdx.x * 256 + threadIdx.x;
    if (i >= n4) return;
    float4 v = ((const float4*)in)[i];
    ushort4 r;
    r.x = f2b(v.x); r.y = f2b(v.y); r.z = f2b(v.z); r.w = f2b(v.w);
    ((ushort4*)out)[i] = r;
}

// out[c][r] = bf16(in[r][c]); R,C multiples of 32; block (32,8)
__global__ void transpose_f32_bf16(const float* __restrict__ in, u16* __restrict__ out, int R, int C) {
    __shared__ float tile[32][33];
    const int tx = threadIdx.x, ty = threadIdx.y;
    const int c0 = blockIdx.x * 32, r0 = blockIdx.y * 32;
#pragma unroll
    for (int j = 0; j < 32; j += 8)
        tile[ty + j][tx] = in[(size_t)(r0 + ty + j) * C + c0 + tx];
    __syncthreads();
#pragma unroll
    for (int j = 0; j < 32; j += 8)
        out[(size_t)(c0 + ty + j) * R + r0 + tx] = f2b(tile[tx][ty + j]);
}

// ---------------- GEMM C = A[M,K] * Bt[N,K]^T, bf16 in, f32 acc ----------------
// BM=256 x BN=128, BK=32, 512 thr (8 waves 4Mx2N, 64x64/wave).
// 3-slot LDS = 72 KB. Counted vmcnt(3) -> ONE barrier -> 8 ds_read ->
// STG(t+2) -> 16 MFMA (plateau structure, ~718 TF at this shape).
// q epilogue scale folds 1/sqrt(64) * log2(e) for exp2-domain softmax.

template<int MODE>
__global__ __launch_bounds__(512, 4)
void gemm9(const u16* __restrict__ A, const u16* __restrict__ Bt,
           int N, int K, int nwg,
           u16* __restrict__ oq, u16* __restrict__ ok, u16* __restrict__ ovT,
           float* __restrict__ of)
{
    __shared__ __align__(16) u16 As[3][256 * 32];   // 48 KiB
    __shared__ __align__(16) u16 Bs[3][128 * 32];   // 24 KiB
    const int tid = threadIdx.x;
    const int lane = tid & 63, l15 = lane & 15, g = lane >> 4;
    const int wid = tid >> 6, wm = wid >> 1, wn = wid & 1;

    // row-major-chunked XCD swizzle: sid walks cols fast, row panels slow
    const int gx = N >> 7;                       // col panels of 128
    const int cpx = nwg >> 3;
    const int sid = (blockIdx.x & 7) * cpx + (blockIdx.x >> 3);
    const long row0 = (long)(sid / gx) * 256;
    const long col0 = (long)(sid % gx) * 128;

    const u16* Ag = A + row0 * K;
    const u16* Bg = Bt + col0 * K;

    const f32x4 z4 = {0.f, 0.f, 0.f, 0.f};
    f32x4 acc[4][4];
#pragma unroll
    for (int i = 0; i < 4; i++)
#pragma unroll
        for (int n = 0; n < 4; n++) acc[i][n] = z4;

    const int swz = (l15 >> 1) & 3;   // read-side chunk XOR == (row>>1)&3

#define STG(t_, s_) do { const int ko = (t_) << 5;                                                 \
        { const int c = tid;       const int r_ = c >> 2;                                          \
          gload16(Ag + (size_t)r_ * K + ko + ((((c & 3) ^ ((r_ >> 1) & 3))) << 3), &As[s_][c << 3]); } \
        { const int c = tid + 512; const int r_ = c >> 2;                                          \
          gload16(Ag + (size_t)r_ * K + ko + ((((c & 3) ^ ((r_ >> 1) & 3))) << 3), &As[s_][c << 3]); } \
        { const int c = tid;       const int r_ = c >> 2;                                          \
          gload16(Bg + (size_t)r_ * K + ko + ((((c & 3) ^ ((r_ >> 1) & 3))) << 3), &Bs[s_][c << 3]); } \
    } while (0)

    const int NT = K >> 5;   // 32
    STG(0, 0);
    STG(1, 1);
    int sc = 0;
    for (int t = 0; t < NT; ++t) {
        if (t < NT - 1) asm volatile("s_waitcnt vmcnt(3)" ::: "memory");  // tile t landed; t+1 in flight
        else            asm volatile("s_waitcnt vmcnt(0)" ::: "memory");
        __builtin_amdgcn_s_barrier();     // all waves' tile-t chunks visible
        bf16x8 af[4], bfr[4];
#pragma unroll
        for (int m = 0; m < 4; m++)
            af[m]  = *(const bf16x8*)&As[sc][(wm * 64 + m * 16 + l15) * 32 + ((g ^ swz) << 3)];
#pragma unroll
        for (int n = 0; n < 4; n++)
            bfr[n] = *(const bf16x8*)&Bs[sc][(wn * 64 + n * 16 + l15) * 32 + ((g ^ swz) << 3)];
        const int sn = (sc == 0) ? 2 : sc - 1;         // slot (t+2)%3 (freed at last barrier)
        if (t + 2 < NT) STG(t + 2, sn);
        __builtin_amdgcn_s_setprio(1);
#pragma unroll
        for (int m = 0; m < 4; m++)
#pragma unroll
            for (int n = 0; n < 4; n++)
                acc[m][n] = __builtin_amdgcn_mfma_f32_16x16x32_bf16(af[m], bfr[n], acc[m][n], 0, 0, 0);
        __builtin_amdgcn_s_setprio(0);
        sc = (sc == 2) ? 0 : sc + 1;
    }
#undef STG

    if (MODE == 0) {
        const int which = (int)(col0 >> 10);
        const long b = row0 >> 11;
#pragma unroll
        for (int m = 0; m < 4; m++) {
            const long r = row0 + wm * 64 + m * 16 + g * 4;
            const long t = r & (TT - 1);
#pragma unroll
            for (int n = 0; n < 4; n++) {
                const long c = col0 + wn * 64 + n * 16 + l15;
                const int h  = (int)((c >> 6) & 15);
                const int hd = (int)(c & 63);
                if (which == 0) {
                    // q scaled by (1/8) * log2(e): softmax runs in exp2 domain
#pragma unroll
                    for (int e = 0; e < 4; e++)
                        oq[((b * NH + h) * TT + t + e) * HD + hd] = f2b(acc[m][n][e] * 0.18033688f);
                } else if (which == 1) {
#pragma unroll
                    for (int e = 0; e < 4; e++)
                        ok[((b * NH + h) * TT + t + e) * HD + hd] = f2b(acc[m][n][e]);
                } else {
                    ushort4 pk;
                    pk.x = f2b(acc[m][n][0]); pk.y = f2b(acc[m][n][1]);
                    pk.z = f2b(acc[m][n][2]); pk.w = f2b(acc[m][n][3]);
                    *(ushort4*)&ovT[((b * NH + h) * HD + hd) * TT + t] = pk;
                }
            }
        }
    } else {
#pragma unroll
        for (int m = 0; m < 4; m++) {
            const long r = row0 + wm * 64 + m * 16 + g * 4;
#pragma unroll
            for (int n = 0; n < 4; n++) {
                const long c = col0 + wn * 64 + n * 16 + l15;
#pragma unroll
                for (int e = 0; e < 4; e++)
                    of[(r + e) * (long)N + c] = acc[m][n][e];
            }
        }
    }
}

// ---------------- flash attention (r9-exact staged structure, exp2 domain) ----------------
// 1D grid: blockIdx.x -> (qt heavy-first, bh). 256 threads (4 waves x 32 q).
// KV tiles of 64 keys, double-buffered (2-slot), counted vmcnt(4), raw s_barrier x2.
// K/V LDS XOR-swizzled (chunk ^ row&7, via pre-swizzled global src).
// QK^T SWAPPED: s = mfma(K,Q) -> q = lane&15, key = g*4+e (in-lane row).
// In-register online softmax (exp2 domain; q pre-scaled by log2e/8 in gemm1).
// P repacked through per-wave LDS as 8B granules, granule ^ l15 swizzle.

__global__ __launch_bounds__(256, 3)
void attn_fwd(const u16* __restrict__ gq, const u16* __restrict__ gk,
              const u16* __restrict__ gvT, u16* __restrict__ o)
{
    __shared__ __align__(16) u16 Klds[2][64 * 64];   // [key][hd] swizzled
    __shared__ __align__(16) u16 Vlds[2][64 * 64];   // [hd][key] swizzled
    __shared__ __align__(16) u16 Plds[4][32 * 64];   // per-wave [q][16 x 8B granules]

    const int tid = threadIdx.x;
    const int wv = tid >> 6, lane = tid & 63, l15 = lane & 15, g = lane >> 4;
    const int bh = blockIdx.x & 63;
    const int qt = 15 - (blockIdx.x >> 6);       // heavy tiles dispatch first
    const int q0 = qt * 128;
    const int qw0 = q0 + wv * 32;

    const u16* qbase = gq + (size_t)bh * TT * HD;
    const u16* kbase = gk + (size_t)bh * TT * HD;
    const u16* vbase = gvT + (size_t)bh * HD * TT;

    const float NEG_INF = -__builtin_inff();
    const f32x4 z4 = {0.f, 0.f, 0.f, 0.f};

    bf16x8 qf[2][2];
#pragma unroll
    for (int qi = 0; qi < 2; qi++)
#pragma unroll
        for (int hs = 0; hs < 2; hs++)
            qf[qi][hs] = *(const bf16x8*)(qbase + (size_t)(qw0 + qi * 16 + l15) * HD + hs * 32 + g * 8);

    f32x4 o_acc[2][4];
    float m[2], ls[2];
#pragma unroll
    for (int qi = 0; qi < 2; qi++) {
#pragma unroll
        for (int n = 0; n < 4; n++) o_acc[qi][n] = z4;
        m[qi] = NEG_INF; ls[qi] = 0.f;
    }

    // staging lane roles (same for K and V): per call each thread loads 2 chunks of each
    const int r0_ = tid >> 3, c0_ = tid & 7;            // chunk (r0_, c0_)
    const int r1_ = (tid + 256) >> 3, c1_ = (tid + 256) & 7;

#define STAGE(buf, k0s)                                                                    \
    do {                                                                                   \
        gload16(kbase + (size_t)((k0s) + r0_) * HD + ((c0_ ^ (r0_ & 7)) * 8), &Klds[buf][tid * 8]);          \
        gload16(kbase + (size_t)((k0s) + r1_) * HD + ((c1_ ^ (r1_ & 7)) * 8), &Klds[buf][(tid + 256) * 8]);  \
        gload16(vbase + (size_t)r0_ * TT + (k0s) + ((c0_ ^ (r0_ & 7)) * 8), &Vlds[buf][tid * 8]);            \
        gload16(vbase + (size_t)r1_ * TT + (k0s) + ((c1_ ^ (r1_ & 7)) * 8), &Vlds[buf][(tid + 256) * 8]);    \
    } while (0)

    const int nkt = q0 / 64 + 2;
    STAGE(0, 0);
    for (int kt = 0; kt < nkt; ++kt) {
        const int k0 = kt * 64;
        const int cur = kt & 1;
        if (kt + 1 < nkt) {
            STAGE(cur ^ 1, k0 + 64);
            asm volatile("s_waitcnt vmcnt(4)" ::: "memory");  // tile kt's 4 loads done
        } else {
            asm volatile("s_waitcnt vmcnt(0)" ::: "memory");
        }
        __builtin_amdgcn_s_barrier();
        if (k0 <= qw0 + 31) {
            const int sw = l15 & 7;   // row&7 for K rows (kb*16+l15) and V rows (n*16+l15)
            // swapped QK^T: s2[qi][kb]: q = qi*16 + l15, key = k0 + kb*16 + g*4 + e
            f32x4 s2[2][4];
            __builtin_amdgcn_s_setprio(1);
#pragma unroll
            for (int kb = 0; kb < 4; kb++) {
                bf16x8 kf0 = *(const bf16x8*)&Klds[cur][(kb * 16 + l15) * 64 + ((g ^ sw) * 8)];
                bf16x8 kf1 = *(const bf16x8*)&Klds[cur][(kb * 16 + l15) * 64 + (((4 + g) ^ sw) * 8)];
#pragma unroll
                for (int qi = 0; qi < 2; qi++) {
                    f32x4 t0 = __builtin_amdgcn_mfma_f32_16x16x32_bf16(kf0, qf[qi][0], z4, 0, 0, 0);
                    s2[qi][kb] = __builtin_amdgcn_mfma_f32_16x16x32_bf16(kf1, qf[qi][1], t0, 0, 0, 0);
                }
            }
            __builtin_amdgcn_s_setprio(0);
            if (k0 + 63 > qw0) {
#pragma unroll
                for (int qi = 0; qi < 2; qi++)
#pragma unroll
                    for (int kb = 0; kb < 4; kb++)
#pragma unroll
                        for (int e = 0; e < 4; e++) {
                            const int kk = k0 + kb * 16 + g * 4 + e;
                            const int qq = qw0 + qi * 16 + l15;
                            if (kk > qq) s2[qi][kb][e] = NEG_INF;
                        }
            }
            // in-register online softmax, exp2 domain (q = l15 per lane)
#pragma unroll
            for (int qi = 0; qi < 2; qi++) {
                f32x4 mx = s2[qi][0];
#pragma unroll
                for (int kb = 1; kb < 4; kb++)
#pragma unroll
                    for (int e = 0; e < 4; e++) mx[e] = fmaxf(mx[e], s2[qi][kb][e]);
                float pmax = fmaxf(fmaxf(mx[0], mx[1]), fmaxf(mx[2], mx[3]));
                pmax = fmaxf(pmax, __shfl_xor(pmax, 16));
                pmax = fmaxf(pmax, __shfl_xor(pmax, 32));
                float mn = m[qi];
                const int resc = !__all(pmax <= mn + 11.541560f);   // defer-max (2^11.54 = e^8)
                if (resc) {
                    const float mold = mn;
                    mn = fmaxf(mold, pmax);
                    m[qi] = mn;
                    const float sc2 = exp2f(mold - mn);
                    ls[qi] *= sc2;
#pragma unroll
                    for (int e = 0; e < 4; e++) {
                        const float sce = __shfl(sc2, (lane & 48) + (((lane >> 4) & 3) << 2) + e);
#pragma unroll
                        for (int n = 0; n < 4; n++) o_acc[qi][n][e] *= sce;
                    }
                }
                const int prow = qi * 16 + l15;
                u16* pb = &Plds[wv][prow * 64];
                float rsum = 0.f;
#pragma unroll
                for (int kb = 0; kb < 4; kb++) {
                    const float p0 = exp2f(s2[qi][kb][0] - mn);
                    const float p1 = exp2f(s2[qi][kb][1] - mn);
                    const float p2 = exp2f(s2[qi][kb][2] - mn);
                    const float p3 = exp2f(s2[qi][kb][3] - mn);
                    rsum += (p0 + p1) + (p2 + p3);
                    ushort4 pk;
                    pk.x = b16(p0); pk.y = b16(p1); pk.z = b16(p2); pk.w = b16(p3);
                    *(ushort4*)&pb[(((kb << 2) + g) ^ l15) * 4] = pk;
                }
                rsum += __shfl_xor(rsum, 16);
                rsum += __shfl_xor(rsum, 32);
                ls[qi] += rsum;
            }
            asm volatile("s_waitcnt lgkmcnt(0)" ::: "memory");
            // PV: A = P (row q=l15, keys g*8+j), B = V^T
            const int sw2 = l15 & 7;
#pragma unroll
            for (int ks = 0; ks < 2; ks++) {
                bf16x8 vf[4];
#pragma unroll
                for (int n = 0; n < 4; n++)
                    vf[n] = *(const bf16x8*)&Vlds[cur][(n * 16 + l15) * 64 + (((ks * 4 + g) ^ sw2) * 8)];
                __builtin_amdgcn_s_setprio(1);
#pragma unroll
                for (int qi = 0; qi < 2; qi++) {
                    const u16* pb = &Plds[wv][(qi * 16 + l15) * 64];
                    const int G0 = ((ks << 3) + (g << 1)) ^ l15;
                    const int G1 = ((ks << 3) + (g << 1) + 1) ^ l15;
                    const uint2 ra = *(const uint2*)&pb[G0 * 4];
                    const uint2 rb = *(const uint2*)&pb[G1 * 4];
                    union { uint32_t w[4]; bf16x8 v; } pu;
                    pu.w[0] = ra.x; pu.w[1] = ra.y; pu.w[2] = rb.x; pu.w[3] = rb.y;
#pragma unroll
                    for (int n = 0; n < 4; n++)
                        o_acc[qi][n] = __builtin_amdgcn_mfma_f32_16x16x32_bf16(pu.v, vf[n], o_acc[qi][n], 0, 0, 0);
                }
                __builtin_amdgcn_s_setprio(0);
            }
        }
        __builtin_amdgcn_s_barrier();
    }
#undef STAGE

    const int b = bh >> 4, h = bh & 15;
#pragma unroll
    for (int qi = 0; qi < 2; qi++) {
        const float linv = 1.f / ls[qi];
#pragma unroll
        for (int e = 0; e < 4; e++) {
            const float inv = __shfl(linv, (lane & 48) + (((lane >> 4) & 3) << 2) + e);
            const int t = qw0 + qi * 16 + g * 4 + e;
#pragma unroll
            for (int n = 0; n < 4; n++)
                o[((size_t)(b * TT + t)) * DD + h * HD + n * 16 + l15] = b16(o_acc[qi][n][e] * inv);
        }
    }
}

// ---------------- launch ----------------

extern "C" void kernel_launch(void* const* d_in, const int* in_sizes, int n_in,
                              void* d_out, int out_size, void* d_ws, size_t ws_size,
                              hipStream_t stream)
{
    const float* x     = (const float*)d_in[0];
    const float* w_qkv = (const float*)d_in[1];
    const float* w_o   = (const float*)d_in[2];
    float* out = (float*)d_out;
    char* ws = (char*)d_ws;

    u16* xb    = (u16*)(ws);                 // 8192x1024        16 MB
    u16* wqkvT = (u16*)(ws + 16777216);      // 3072x1024         6 MB
    u16* woT   = (u16*)(ws + 23068672);      // 1024x1024         2 MB
    u16* wsq   = (u16*)(ws + 25165824);      // [B,H,T,64]       16 MB
    u16* wsk   = (u16*)(ws + 41943040);      // [B,H,T,64]       16 MB
    u16* wsvT  = (u16*)(ws + 58720256);      // [B,H,64,T]       16 MB
    u16* attno = (u16*)(ws + 75497472);      // [B*T, D]         16 MB

    f32_to_bf16_vec<<<8192, 256, 0, stream>>>(x, xb, 2097152);
    dim3 tb(32, 8);
    transpose_f32_bf16<<<dim3(96, 32), tb, 0, stream>>>(w_qkv, wqkvT, 1024, 3072);
    transpose_f32_bf16<<<dim3(32, 32), tb, 0, stream>>>(w_o,   woT,   1024, 1024);

    gemm9<0><<<768, 512, 0, stream>>>(xb, wqkvT, 3072, 1024, 768, wsq, wsk, wsvT, nullptr);
    attn_fwd<<<1024, 256, 0, stream>>>(wsq, wsk, wsvT, attno);
    gemm9<1><<<256, 512, 0, stream>>>(attno, woT, 1024, 1024, 256, nullptr, nullptr, nullptr, out);
}

// Round 13
// 163.060 us; speedup vs baseline: 1.4271x; 1.0485x over previous
//
#include <hip/hip_runtime.h>
#include <hip/hip_bf16.h>
#include <stdint.h>

#define HD 64
#define NH 16
#define TT 2048
#define DD 1024

typedef uint16_t u16;
typedef __bf16 bf16_t;
typedef bf16_t bf16x8 __attribute__((ext_vector_type(8)));
typedef float f32x4 __attribute__((ext_vector_type(4)));

__device__ __forceinline__ u16 f2b(float f) {
    union { float f; uint32_t u; } v; v.f = f;
    uint32_t u = v.u;
    u += 0x7fff + ((u >> 16) & 1);   // RNE
    return (u16)(u >> 16);
}

__device__ __forceinline__ u16 b16(float f) {
    union { __bf16 h; u16 u; } c; c.h = (__bf16)f; return c.u;  // HW cvt (RNE)
}

// native v_exp_f32: D = 2^S0 (single instruction; exp2f libm is ~10 VALU ops)
__device__ __forceinline__ float ex2(float x) { return __builtin_amdgcn_exp2f(x); }

__device__ __forceinline__ void gload16(const void* g, void* l) {
    __builtin_amdgcn_global_load_lds(
        (__attribute__((address_space(1))) void*)g,
        (__attribute__((address_space(3))) void*)l, 16, 0, 0);
}

// ---------------- converts ----------------

__global__ void f32_to_bf16_vec(const float* __restrict__ in, u16* __restrict__ out, int n4) {
    int i = blockIdx.x * 256 + threadIdx.x;
    if (i >= n4) return;
    float4 v = ((const float4*)in)[i];
    ushort4 r;
    r.x = f2b(v.x); r.y = f2b(v.y); r.z = f2b(v.z); r.w = f2b(v.w);
    ((ushort4*)out)[i] = r;
}

// out[c][r] = bf16(in[r][c]); R,C multiples of 32; block (32,8)
__global__ void transpose_f32_bf16(const float* __restrict__ in, u16* __restrict__ out, int R, int C) {
    __shared__ float tile[32][33];
    const int tx = threadIdx.x, ty = threadIdx.y;
    const int c0 = blockIdx.x * 32, r0 = blockIdx.y * 32;
#pragma unroll
    for (int j = 0; j < 32; j += 8)
        tile[ty + j][tx] = in[(size_t)(r0 + ty + j) * C + c0 + tx];
    __syncthreads();
#pragma unroll
    for (int j = 0; j < 32; j += 8)
        out[(size_t)(c0 + ty + j) * R + r0 + tx] = f2b(tile[tx][ty + j]);
}

// ---------------- GEMM C = A[M,K] * Bt[N,K]^T, bf16 in, f32 acc ----------------
// BM=256 x BN=128, BK=32, 512 thr (8 waves 4Mx2N, 64x64/wave).
// 3-slot LDS = 72 KB. Counted vmcnt(3) -> ONE barrier -> 8 ds_read ->
// STG(t+2) -> 16 MFMA (plateau structure, ~718 TF at this shape).
// q epilogue scale folds 1/sqrt(64) * log2(e) for exp2-domain softmax.

template<int MODE>
__global__ __launch_bounds__(512, 4)
void gemm9(const u16* __restrict__ A, const u16* __restrict__ Bt,
           int N, int K, int nwg,
           u16* __restrict__ oq, u16* __restrict__ ok, u16* __restrict__ ovT,
           float* __restrict__ of)
{
    __shared__ __align__(16) u16 As[3][256 * 32];   // 48 KiB
    __shared__ __align__(16) u16 Bs[3][128 * 32];   // 24 KiB
    const int tid = threadIdx.x;
    const int lane = tid & 63, l15 = lane & 15, g = lane >> 4;
    const int wid = tid >> 6, wm = wid >> 1, wn = wid & 1;

    // row-major-chunked XCD swizzle: sid walks cols fast, row panels slow
    const int gx = N >> 7;                       // col panels of 128
    const int cpx = nwg >> 3;
    const int sid = (blockIdx.x & 7) * cpx + (blockIdx.x >> 3);
    const long row0 = (long)(sid / gx) * 256;
    const long col0 = (long)(sid % gx) * 128;

    const u16* Ag = A + row0 * K;
    const u16* Bg = Bt + col0 * K;

    const f32x4 z4 = {0.f, 0.f, 0.f, 0.f};
    f32x4 acc[4][4];
#pragma unroll
    for (int i = 0; i < 4; i++)
#pragma unroll
        for (int n = 0; n < 4; n++) acc[i][n] = z4;

    const int swz = (l15 >> 1) & 3;   // read-side chunk XOR == (row>>1)&3

#define STG(t_, s_) do { const int ko = (t_) << 5;                                                 \
        { const int c = tid;       const int r_ = c >> 2;                                          \
          gload16(Ag + (size_t)r_ * K + ko + ((((c & 3) ^ ((r_ >> 1) & 3))) << 3), &As[s_][c << 3]); } \
        { const int c = tid + 512; const int r_ = c >> 2;                                          \
          gload16(Ag + (size_t)r_ * K + ko + ((((c & 3) ^ ((r_ >> 1) & 3))) << 3), &As[s_][c << 3]); } \
        { const int c = tid;       const int r_ = c >> 2;                                          \
          gload16(Bg + (size_t)r_ * K + ko + ((((c & 3) ^ ((r_ >> 1) & 3))) << 3), &Bs[s_][c << 3]); } \
    } while (0)

    const int NT = K >> 5;   // 32
    STG(0, 0);
    STG(1, 1);
    int sc = 0;
    for (int t = 0; t < NT; ++t) {
        if (t < NT - 1) asm volatile("s_waitcnt vmcnt(3)" ::: "memory");  // tile t landed; t+1 in flight
        else            asm volatile("s_waitcnt vmcnt(0)" ::: "memory");
        __builtin_amdgcn_s_barrier();     // all waves' tile-t chunks visible
        bf16x8 af[4], bfr[4];
#pragma unroll
        for (int m = 0; m < 4; m++)
            af[m]  = *(const bf16x8*)&As[sc][(wm * 64 + m * 16 + l15) * 32 + ((g ^ swz) << 3)];
#pragma unroll
        for (int n = 0; n < 4; n++)
            bfr[n] = *(const bf16x8*)&Bs[sc][(wn * 64 + n * 16 + l15) * 32 + ((g ^ swz) << 3)];
        const int sn = (sc == 0) ? 2 : sc - 1;         // slot (t+2)%3 (freed at last barrier)
        if (t + 2 < NT) STG(t + 2, sn);
        __builtin_amdgcn_s_setprio(1);
#pragma unroll
        for (int m = 0; m < 4; m++)
#pragma unroll
            for (int n = 0; n < 4; n++)
                acc[m][n] = __builtin_amdgcn_mfma_f32_16x16x32_bf16(af[m], bfr[n], acc[m][n], 0, 0, 0);
        __builtin_amdgcn_s_setprio(0);
        sc = (sc == 2) ? 0 : sc + 1;
    }
#undef STG

    if (MODE == 0) {
        const int which = (int)(col0 >> 10);
        const long b = row0 >> 11;
#pragma unroll
        for (int m = 0; m < 4; m++) {
            const long r = row0 + wm * 64 + m * 16 + g * 4;
            const long t = r & (TT - 1);
#pragma unroll
            for (int n = 0; n < 4; n++) {
                const long c = col0 + wn * 64 + n * 16 + l15;
                const int h  = (int)((c >> 6) & 15);
                const int hd = (int)(c & 63);
                if (which == 0) {
                    // q scaled by (1/8) * log2(e): softmax runs in exp2 domain
#pragma unroll
                    for (int e = 0; e < 4; e++)
                        oq[((b * NH + h) * TT + t + e) * HD + hd] = f2b(acc[m][n][e] * 0.18033688f);
                } else if (which == 1) {
#pragma unroll
                    for (int e = 0; e < 4; e++)
                        ok[((b * NH + h) * TT + t + e) * HD + hd] = f2b(acc[m][n][e]);
                } else {
                    ushort4 pk;
                    pk.x = f2b(acc[m][n][0]); pk.y = f2b(acc[m][n][1]);
                    pk.z = f2b(acc[m][n][2]); pk.w = f2b(acc[m][n][3]);
                    *(ushort4*)&ovT[((b * NH + h) * HD + hd) * TT + t] = pk;
                }
            }
        }
    } else {
#pragma unroll
        for (int m = 0; m < 4; m++) {
            const long r = row0 + wm * 64 + m * 16 + g * 4;
#pragma unroll
            for (int n = 0; n < 4; n++) {
                const long c = col0 + wn * 64 + n * 16 + l15;
#pragma unroll
                for (int e = 0; e < 4; e++)
                    of[(r + e) * (long)N + c] = acc[m][n][e];
            }
        }
    }
}

// ---------------- flash attention (r9 staged structure, exp2 via v_exp_f32) ----------------
// 1D grid: blockIdx.x -> (qt heavy-first, bh). 256 threads (4 waves x 32 q).
// KV tiles of 64 keys, double-buffered (2-slot), counted vmcnt(4), raw s_barrier x2.
// K/V LDS XOR-swizzled (chunk ^ row&7, via pre-swizzled global src).
// QK^T SWAPPED: s = mfma(K,Q) -> q = lane&15, key = g*4+e (in-lane row).
// In-register online softmax: exp2 domain (q pre-scaled by log2e/8 in gemm1),
// ex2() = __builtin_amdgcn_exp2f = 1 v_exp_f32 (libm exp2f was ~10 VALU ops - r12 lesson).
// P repacked through per-wave LDS as 8B granules, granule ^ l15 swizzle.

__global__ __launch_bounds__(256, 3)
void attn_fwd(const u16* __restrict__ gq, const u16* __restrict__ gk,
              const u16* __restrict__ gvT, u16* __restrict__ o)
{
    __shared__ __align__(16) u16 Klds[2][64 * 64];   // [key][hd] swizzled
    __shared__ __align__(16) u16 Vlds[2][64 * 64];   // [hd][key] swizzled
    __shared__ __align__(16) u16 Plds[4][32 * 64];   // per-wave [q][16 x 8B granules]

    const int tid = threadIdx.x;
    const int wv = tid >> 6, lane = tid & 63, l15 = lane & 15, g = lane >> 4;
    const int bh = blockIdx.x & 63;
    const int qt = 15 - (blockIdx.x >> 6);       // heavy tiles dispatch first
    const int q0 = qt * 128;
    const int qw0 = q0 + wv * 32;

    const u16* qbase = gq + (size_t)bh * TT * HD;
    const u16* kbase = gk + (size_t)bh * TT * HD;
    const u16* vbase = gvT + (size_t)bh * HD * TT;

    const float NEG_INF = -__builtin_inff();
    const f32x4 z4 = {0.f, 0.f, 0.f, 0.f};

    bf16x8 qf[2][2];
#pragma unroll
    for (int qi = 0; qi < 2; qi++)
#pragma unroll
        for (int hs = 0; hs < 2; hs++)
            qf[qi][hs] = *(const bf16x8*)(qbase + (size_t)(qw0 + qi * 16 + l15) * HD + hs * 32 + g * 8);

    f32x4 o_acc[2][4];
    float m[2], ls[2];
#pragma unroll
    for (int qi = 0; qi < 2; qi++) {
#pragma unroll
        for (int n = 0; n < 4; n++) o_acc[qi][n] = z4;
        m[qi] = NEG_INF; ls[qi] = 0.f;
    }

    // staging lane roles (same for K and V): per call each thread loads 2 chunks of each
    const int r0_ = tid >> 3, c0_ = tid & 7;            // chunk (r0_, c0_)
    const int r1_ = (tid + 256) >> 3, c1_ = (tid + 256) & 7;

#define STAGE(buf, k0s)                                                                    \
    do {                                                                                   \
        gload16(kbase + (size_t)((k0s) + r0_) * HD + ((c0_ ^ (r0_ & 7)) * 8), &Klds[buf][tid * 8]);          \
        gload16(kbase + (size_t)((k0s) + r1_) * HD + ((c1_ ^ (r1_ & 7)) * 8), &Klds[buf][(tid + 256) * 8]);  \
        gload16(vbase + (size_t)r0_ * TT + (k0s) + ((c0_ ^ (r0_ & 7)) * 8), &Vlds[buf][tid * 8]);            \
        gload16(vbase + (size_t)r1_ * TT + (k0s) + ((c1_ ^ (r1_ & 7)) * 8), &Vlds[buf][(tid + 256) * 8]);    \
    } while (0)

    const int nkt = q0 / 64 + 2;
    STAGE(0, 0);
    for (int kt = 0; kt < nkt; ++kt) {
        const int k0 = kt * 64;
        const int cur = kt & 1;
        if (kt + 1 < nkt) {
            STAGE(cur ^ 1, k0 + 64);
            asm volatile("s_waitcnt vmcnt(4)" ::: "memory");  // tile kt's 4 loads done
        } else {
            asm volatile("s_waitcnt vmcnt(0)" ::: "memory");
        }
        __builtin_amdgcn_s_barrier();
        if (k0 <= qw0 + 31) {
            const int sw = l15 & 7;   // row&7 for K rows (kb*16+l15) and V rows (n*16+l15)
            // swapped QK^T: s2[qi][kb]: q = qi*16 + l15, key = k0 + kb*16 + g*4 + e
            f32x4 s2[2][4];
            __builtin_amdgcn_s_setprio(1);
#pragma unroll
            for (int kb = 0; kb < 4; kb++) {
                bf16x8 kf0 = *(const bf16x8*)&Klds[cur][(kb * 16 + l15) * 64 + ((g ^ sw) * 8)];
                bf16x8 kf1 = *(const bf16x8*)&Klds[cur][(kb * 16 + l15) * 64 + (((4 + g) ^ sw) * 8)];
#pragma unroll
                for (int qi = 0; qi < 2; qi++) {
                    f32x4 t0 = __builtin_amdgcn_mfma_f32_16x16x32_bf16(kf0, qf[qi][0], z4, 0, 0, 0);
                    s2[qi][kb] = __builtin_amdgcn_mfma_f32_16x16x32_bf16(kf1, qf[qi][1], t0, 0, 0, 0);
                }
            }
            __builtin_amdgcn_s_setprio(0);
            if (k0 + 63 > qw0) {
#pragma unroll
                for (int qi = 0; qi < 2; qi++)
#pragma unroll
                    for (int kb = 0; kb < 4; kb++)
#pragma unroll
                        for (int e = 0; e < 4; e++) {
                            const int kk = k0 + kb * 16 + g * 4 + e;
                            const int qq = qw0 + qi * 16 + l15;
                            if (kk > qq) s2[qi][kb][e] = NEG_INF;
                        }
            }
            // in-register online softmax, exp2 domain (q = l15 per lane)
#pragma unroll
            for (int qi = 0; qi < 2; qi++) {
                f32x4 mx = s2[qi][0];
#pragma unroll
                for (int kb = 1; kb < 4; kb++)
#pragma unroll
                    for (int e = 0; e < 4; e++) mx[e] = fmaxf(mx[e], s2[qi][kb][e]);
                float pmax = fmaxf(fmaxf(mx[0], mx[1]), fmaxf(mx[2], mx[3]));
                pmax = fmaxf(pmax, __shfl_xor(pmax, 16));
                pmax = fmaxf(pmax, __shfl_xor(pmax, 32));
                float mn = m[qi];
                const int resc = !__all(pmax <= mn + 11.541560f);   // defer-max (2^11.54 = e^8)
                if (resc) {
                    const float mold = mn;
                    mn = fmaxf(mold, pmax);
                    m[qi] = mn;
                    const float sc2 = ex2(mold - mn);
                    ls[qi] *= sc2;
#pragma unroll
                    for (int e = 0; e < 4; e++) {
                        const float sce = __shfl(sc2, (lane & 48) + (((lane >> 4) & 3) << 2) + e);
#pragma unroll
                        for (int n = 0; n < 4; n++) o_acc[qi][n][e] *= sce;
                    }
                }
                const int prow = qi * 16 + l15;
                u16* pb = &Plds[wv][prow * 64];
                float rsum = 0.f;
#pragma unroll
                for (int kb = 0; kb < 4; kb++) {
                    const float p0 = ex2(s2[qi][kb][0] - mn);
                    const float p1 = ex2(s2[qi][kb][1] - mn);
                    const float p2 = ex2(s2[qi][kb][2] - mn);
                    const float p3 = ex2(s2[qi][kb][3] - mn);
                    rsum += (p0 + p1) + (p2 + p3);
                    ushort4 pk;
                    pk.x = b16(p0); pk.y = b16(p1); pk.z = b16(p2); pk.w = b16(p3);
                    *(ushort4*)&pb[(((kb << 2) + g) ^ l15) * 4] = pk;
                }
                rsum += __shfl_xor(rsum, 16);
                rsum += __shfl_xor(rsum, 32);
                ls[qi] += rsum;
            }
            asm volatile("s_waitcnt lgkmcnt(0)" ::: "memory");
            // PV: A = P (row q=l15, keys g*8+j), B = V^T
            const int sw2 = l15 & 7;
#pragma unroll
            for (int ks = 0; ks < 2; ks++) {
                bf16x8 vf[4];
#pragma unroll
                for (int n = 0; n < 4; n++)
                    vf[n] = *(const bf16x8*)&Vlds[cur][(n * 16 + l15) * 64 + (((ks * 4 + g) ^ sw2) * 8)];
                __builtin_amdgcn_s_setprio(1);
#pragma unroll
                for (int qi = 0; qi < 2; qi++) {
                    const u16* pb = &Plds[wv][(qi * 16 + l15) * 64];
                    const int G0 = ((ks << 3) + (g << 1)) ^ l15;
                    const int G1 = ((ks << 3) + (g << 1) + 1) ^ l15;
                    const uint2 ra = *(const uint2*)&pb[G0 * 4];
                    const uint2 rb = *(const uint2*)&pb[G1 * 4];
                    union { uint32_t w[4]; bf16x8 v; } pu;
                    pu.w[0] = ra.x; pu.w[1] = ra.y; pu.w[2] = rb.x; pu.w[3] = rb.y;
#pragma unroll
                    for (int n = 0; n < 4; n++)
                        o_acc[qi][n] = __builtin_amdgcn_mfma_f32_16x16x32_bf16(pu.v, vf[n], o_acc[qi][n], 0, 0, 0);
                }
                __builtin_amdgcn_s_setprio(0);
            }
        }
        __builtin_amdgcn_s_barrier();
    }
#undef STAGE

    const int b = bh >> 4, h = bh & 15;
#pragma unroll
    for (int qi = 0; qi < 2; qi++) {
        const float linv = 1.f / ls[qi];
#pragma unroll
        for (int e = 0; e < 4; e++) {
            const float inv = __shfl(linv, (lane & 48) + (((lane >> 4) & 3) << 2) + e);
            const int t = qw0 + qi * 16 + g * 4 + e;
#pragma unroll
            for (int n = 0; n < 4; n++)
                o[((size_t)(b * TT + t)) * DD + h * HD + n * 16 + l15] = b16(o_acc[qi][n][e] * inv);
        }
    }
}

// ---------------- launch ----------------

extern "C" void kernel_launch(void* const* d_in, const int* in_sizes, int n_in,
                              void* d_out, int out_size, void* d_ws, size_t ws_size,
                              hipStream_t stream)
{
    const float* x     = (const float*)d_in[0];
    const float* w_qkv = (const float*)d_in[1];
    const float* w_o   = (const float*)d_in[2];
    float* out = (float*)d_out;
    char* ws = (char*)d_ws;

    u16* xb    = (u16*)(ws);                 // 8192x1024        16 MB
    u16* wqkvT = (u16*)(ws + 16777216);      // 3072x1024         6 MB
    u16* woT   = (u16*)(ws + 23068672);      // 1024x1024         2 MB
    u16* wsq   = (u16*)(ws + 25165824);      // [B,H,T,64]       16 MB
    u16* wsk   = (u16*)(ws + 41943040);      // [B,H,T,64]       16 MB
    u16* wsvT  = (u16*)(ws + 58720256);      // [B,H,64,T]       16 MB
    u16* attno = (u16*)(ws + 75497472);      // [B*T, D]         16 MB

    f32_to_bf16_vec<<<8192, 256, 0, stream>>>(x, xb, 2097152);
    dim3 tb(32, 8);
    transpose_f32_bf16<<<dim3(96, 32), tb, 0, stream>>>(w_qkv, wqkvT, 1024, 3072);
    transpose_f32_bf16<<<dim3(32, 32), tb, 0, stream>>>(w_o,   woT,   1024, 1024);

    gemm9<0><<<768, 512, 0, stream>>>(xb, wqkvT, 3072, 1024, 768, wsq, wsk, wsvT, nullptr);
    attn_fwd<<<1024, 256, 0, stream>>>(wsq, wsk, wsvT, attno);
    gemm9<1><<<256, 512, 0, stream>>>(attno, woT, 1024, 1024, 256, nullptr, nullptr, nullptr, out);
}

// Round 14
// 157.872 us; speedup vs baseline: 1.4740x; 1.0329x over previous
//
#include <hip/hip_runtime.h>
#include <hip/hip_bf16.h>
#include <stdint.h>

#define HD 64
#define NH 16
#define TT 2048
#define DD 1024

typedef uint16_t u16;
typedef __bf16 bf16_t;
typedef bf16_t bf16x8 __attribute__((ext_vector_type(8)));
typedef float f32x4 __attribute__((ext_vector_type(4)));

__device__ __forceinline__ u16 f2b(float f) {
    union { float f; uint32_t u; } v; v.f = f;
    uint32_t u = v.u;
    u += 0x7fff + ((u >> 16) & 1);   // RNE
    return (u16)(u >> 16);
}

__device__ __forceinline__ u16 b16(float f) {
    union { __bf16 h; u16 u; } c; c.h = (__bf16)f; return c.u;  // HW cvt (RNE)
}

// native v_exp_f32: D = 2^S0 (single instruction; exp2f libm is ~10 VALU ops)
__device__ __forceinline__ float ex2(float x) { return __builtin_amdgcn_exp2f(x); }

__device__ __forceinline__ void gload16(const void* g, void* l) {
    __builtin_amdgcn_global_load_lds(
        (__attribute__((address_space(1))) void*)g,
        (__attribute__((address_space(3))) void*)l, 16, 0, 0);
}

// ---------------- converts ----------------

__global__ void f32_to_bf16_vec(const float* __restrict__ in, u16* __restrict__ out, int n4) {
    int i = blockIdx.x * 256 + threadIdx.x;
    if (i >= n4) return;
    float4 v = ((const float4*)in)[i];
    ushort4 r;
    r.x = f2b(v.x); r.y = f2b(v.y); r.z = f2b(v.z); r.w = f2b(v.w);
    ((ushort4*)out)[i] = r;
}

// out[c][r] = bf16(in[r][c]); R,C multiples of 32; block (32,8)
__global__ void transpose_f32_bf16(const float* __restrict__ in, u16* __restrict__ out, int R, int C) {
    __shared__ float tile[32][33];
    const int tx = threadIdx.x, ty = threadIdx.y;
    const int c0 = blockIdx.x * 32, r0 = blockIdx.y * 32;
#pragma unroll
    for (int j = 0; j < 32; j += 8)
        tile[ty + j][tx] = in[(size_t)(r0 + ty + j) * C + c0 + tx];
    __syncthreads();
#pragma unroll
    for (int j = 0; j < 32; j += 8)
        out[(size_t)(c0 + ty + j) * R + r0 + tx] = f2b(tile[tx][ty + j]);
}

// ---------------- GEMM C = A[M,K] * Bt[N,K]^T, bf16 in, f32 acc ----------------
// gemm10: BM=128 x BN=128, BK=64, 512 thr (8 waves 4Mx2N, 32x64/wave).
// 2-slot LDS = 64 KB -> 2 blocks/CU. 16 sync chains (vs gemm9's 32): per K-tile
// {vmcnt(0) of loads issued a full iteration ago -> ONE barrier -> STG(t+1) into
// the slot freed at this barrier -> 12 ds_read -> 16 MFMA}. Read swizzle
// chunk^(l15&7) at 128B rows = attn's measured-0-conflict pattern (rule 21:
// pre-swizzled global src, linear LDS dest). Row-chunked bijective XCD swizzle.
// Grids EXACT: MODE0 1536 = 3.0 rounds @2/CU, MODE1 512 = 1.0 round.
// MODE 0: scatter epilogue -> q (x log2e/8), k, vT.  MODE 1: f32 store.

template<int MODE>
__global__ __launch_bounds__(512, 4)
void gemm10(const u16* __restrict__ A, const u16* __restrict__ Bt,
            int N, int K, int nwg,
            u16* __restrict__ oq, u16* __restrict__ ok, u16* __restrict__ ovT,
            float* __restrict__ of)
{
    __shared__ __align__(16) u16 As[2][128 * 64];   // 32 KiB
    __shared__ __align__(16) u16 Bs[2][128 * 64];   // 32 KiB
    const int tid = threadIdx.x;
    const int lane = tid & 63, l15 = lane & 15, g = lane >> 4;
    const int wid = tid >> 6, wm = wid >> 1, wn = wid & 1;

    // row-major-chunked XCD swizzle: sid walks cols fast, row panels slow
    const int gx = N >> 7;                       // col panels of 128
    const int cpx = nwg >> 3;
    const int sid = (blockIdx.x & 7) * cpx + (blockIdx.x >> 3);
    const long row0 = (long)(sid / gx) * 128;
    const long col0 = (long)(sid % gx) * 128;

    const u16* Ag = A + row0 * K;
    const u16* Bg = Bt + col0 * K;

    const f32x4 z4 = {0.f, 0.f, 0.f, 0.f};
    f32x4 acc[2][4];
#pragma unroll
    for (int i = 0; i < 2; i++)
#pragma unroll
        for (int n = 0; n < 4; n++) acc[i][n] = z4;

    const int sw = l15 & 7;   // read-side chunk XOR (row&7)

    // per K-tile: A = 1024 16B-chunks (2/thread), B = 1024 (2/thread).
    // row r = c>>3, chunk-in-row = c&7; LDS slot j of row r holds global chunk j^(r&7).
#define STG(t_, s_) do { const int ko = (t_) << 6;                                                  \
        { const int c = tid;       const int r_ = c >> 3;                                           \
          gload16(Ag + (size_t)r_ * K + ko + (((c & 7) ^ (r_ & 7)) << 3), &As[s_][c << 3]); }       \
        { const int c = tid + 512; const int r_ = c >> 3;                                           \
          gload16(Ag + (size_t)r_ * K + ko + (((c & 7) ^ (r_ & 7)) << 3), &As[s_][c << 3]); }       \
        { const int c = tid;       const int r_ = c >> 3;                                           \
          gload16(Bg + (size_t)r_ * K + ko + (((c & 7) ^ (r_ & 7)) << 3), &Bs[s_][c << 3]); }       \
        { const int c = tid + 512; const int r_ = c >> 3;                                           \
          gload16(Bg + (size_t)r_ * K + ko + (((c & 7) ^ (r_ & 7)) << 3), &Bs[s_][c << 3]); }       \
    } while (0)

    const int NT = K >> 6;   // 16
    STG(0, 0);
    for (int t = 0; t < NT; ++t) {
        const int cur = t & 1;
        asm volatile("s_waitcnt vmcnt(0)" ::: "memory");   // tile t's 4 loads (issued 1 iter ago)
        __builtin_amdgcn_s_barrier();                       // slot cur^1 now free (arg: reads of
        if (t + 1 < NT) STG(t + 1, cur ^ 1);                //   t-1 completed before each wave's arrival)
#pragma unroll
        for (int ks = 0; ks < 2; ks++) {
            bf16x8 af[2], bfr[4];
            const int ce = ((ks * 4 + g) ^ sw) << 3;        // swizzled chunk offset (u16 units)
#pragma unroll
            for (int m = 0; m < 2; m++)
                af[m]  = *(const bf16x8*)&As[cur][(wm * 32 + m * 16 + l15) * 64 + ce];
#pragma unroll
            for (int n = 0; n < 4; n++)
                bfr[n] = *(const bf16x8*)&Bs[cur][(wn * 64 + n * 16 + l15) * 64 + ce];
            __builtin_amdgcn_s_setprio(1);
#pragma unroll
            for (int m = 0; m < 2; m++)
#pragma unroll
                for (int n = 0; n < 4; n++)
                    acc[m][n] = __builtin_amdgcn_mfma_f32_16x16x32_bf16(af[m], bfr[n], acc[m][n], 0, 0, 0);
            __builtin_amdgcn_s_setprio(0);
        }
    }
#undef STG

    if (MODE == 0) {
        const int which = (int)(col0 >> 10);
        const long b = row0 >> 11;
#pragma unroll
        for (int m = 0; m < 2; m++) {
            const long r = row0 + wm * 32 + m * 16 + g * 4;
            const long t = r & (TT - 1);
#pragma unroll
            for (int n = 0; n < 4; n++) {
                const long c = col0 + wn * 64 + n * 16 + l15;
                const int h  = (int)((c >> 6) & 15);
                const int hd = (int)(c & 63);
                if (which == 0) {
                    // q scaled by (1/8) * log2(e): softmax runs in exp2 domain
#pragma unroll
                    for (int e = 0; e < 4; e++)
                        oq[((b * NH + h) * TT + t + e) * HD + hd] = f2b(acc[m][n][e] * 0.18033688f);
                } else if (which == 1) {
#pragma unroll
                    for (int e = 0; e < 4; e++)
                        ok[((b * NH + h) * TT + t + e) * HD + hd] = f2b(acc[m][n][e]);
                } else {
                    ushort4 pk;
                    pk.x = f2b(acc[m][n][0]); pk.y = f2b(acc[m][n][1]);
                    pk.z = f2b(acc[m][n][2]); pk.w = f2b(acc[m][n][3]);
                    *(ushort4*)&ovT[((b * NH + h) * HD + hd) * TT + t] = pk;
                }
            }
        }
    } else {
#pragma unroll
        for (int m = 0; m < 2; m++) {
            const long r = row0 + wm * 32 + m * 16 + g * 4;
#pragma unroll
            for (int n = 0; n < 4; n++) {
                const long c = col0 + wn * 64 + n * 16 + l15;
#pragma unroll
                for (int e = 0; e < 4; e++)
                    of[(r + e) * (long)N + c] = acc[m][n][e];
            }
        }
    }
}

// ---------------- flash attention (r13-exact: staged, exp2 via v_exp_f32) ----------------
// 1D grid: blockIdx.x -> (qt heavy-first, bh). 256 threads (4 waves x 32 q).
// KV tiles of 64 keys, double-buffered (2-slot), counted vmcnt(4), raw s_barrier x2.
// K/V LDS XOR-swizzled (chunk ^ row&7, via pre-swizzled global src).
// QK^T SWAPPED: s = mfma(K,Q) -> q = lane&15, key = g*4+e (in-lane row).
// In-register online softmax: exp2 domain (q pre-scaled by log2e/8 in gemm),
// ex2() = __builtin_amdgcn_exp2f = 1 v_exp_f32.
// P repacked through per-wave LDS as 8B granules, granule ^ l15 swizzle.

__global__ __launch_bounds__(256, 3)
void attn_fwd(const u16* __restrict__ gq, const u16* __restrict__ gk,
              const u16* __restrict__ gvT, u16* __restrict__ o)
{
    __shared__ __align__(16) u16 Klds[2][64 * 64];   // [key][hd] swizzled
    __shared__ __align__(16) u16 Vlds[2][64 * 64];   // [hd][key] swizzled
    __shared__ __align__(16) u16 Plds[4][32 * 64];   // per-wave [q][16 x 8B granules]

    const int tid = threadIdx.x;
    const int wv = tid >> 6, lane = tid & 63, l15 = lane & 15, g = lane >> 4;
    const int bh = blockIdx.x & 63;
    const int qt = 15 - (blockIdx.x >> 6);       // heavy tiles dispatch first
    const int q0 = qt * 128;
    const int qw0 = q0 + wv * 32;

    const u16* qbase = gq + (size_t)bh * TT * HD;
    const u16* kbase = gk + (size_t)bh * TT * HD;
    const u16* vbase = gvT + (size_t)bh * HD * TT;

    const float NEG_INF = -__builtin_inff();
    const f32x4 z4 = {0.f, 0.f, 0.f, 0.f};

    bf16x8 qf[2][2];
#pragma unroll
    for (int qi = 0; qi < 2; qi++)
#pragma unroll
        for (int hs = 0; hs < 2; hs++)
            qf[qi][hs] = *(const bf16x8*)(qbase + (size_t)(qw0 + qi * 16 + l15) * HD + hs * 32 + g * 8);

    f32x4 o_acc[2][4];
    float m[2], ls[2];
#pragma unroll
    for (int qi = 0; qi < 2; qi++) {
#pragma unroll
        for (int n = 0; n < 4; n++) o_acc[qi][n] = z4;
        m[qi] = NEG_INF; ls[qi] = 0.f;
    }

    // staging lane roles (same for K and V): per call each thread loads 2 chunks of each
    const int r0_ = tid >> 3, c0_ = tid & 7;            // chunk (r0_, c0_)
    const int r1_ = (tid + 256) >> 3, c1_ = (tid + 256) & 7;

#define STAGE(buf, k0s)                                                                    \
    do {                                                                                   \
        gload16(kbase + (size_t)((k0s) + r0_) * HD + ((c0_ ^ (r0_ & 7)) * 8), &Klds[buf][tid * 8]);          \
        gload16(kbase + (size_t)((k0s) + r1_) * HD + ((c1_ ^ (r1_ & 7)) * 8), &Klds[buf][(tid + 256) * 8]);  \
        gload16(vbase + (size_t)r0_ * TT + (k0s) + ((c0_ ^ (r0_ & 7)) * 8), &Vlds[buf][tid * 8]);            \
        gload16(vbase + (size_t)r1_ * TT + (k0s) + ((c1_ ^ (r1_ & 7)) * 8), &Vlds[buf][(tid + 256) * 8]);    \
    } while (0)

    const int nkt = q0 / 64 + 2;
    STAGE(0, 0);
    for (int kt = 0; kt < nkt; ++kt) {
        const int k0 = kt * 64;
        const int cur = kt & 1;
        if (kt + 1 < nkt) {
            STAGE(cur ^ 1, k0 + 64);
            asm volatile("s_waitcnt vmcnt(4)" ::: "memory");  // tile kt's 4 loads done
        } else {
            asm volatile("s_waitcnt vmcnt(0)" ::: "memory");
        }
        __builtin_amdgcn_s_barrier();
        if (k0 <= qw0 + 31) {
            const int sw = l15 & 7;   // row&7 for K rows (kb*16+l15) and V rows (n*16+l15)
            // swapped QK^T: s2[qi][kb]: q = qi*16 + l15, key = k0 + kb*16 + g*4 + e
            f32x4 s2[2][4];
            __builtin_amdgcn_s_setprio(1);
#pragma unroll
            for (int kb = 0; kb < 4; kb++) {
                bf16x8 kf0 = *(const bf16x8*)&Klds[cur][(kb * 16 + l15) * 64 + ((g ^ sw) * 8)];
                bf16x8 kf1 = *(const bf16x8*)&Klds[cur][(kb * 16 + l15) * 64 + (((4 + g) ^ sw) * 8)];
#pragma unroll
                for (int qi = 0; qi < 2; qi++) {
                    f32x4 t0 = __builtin_amdgcn_mfma_f32_16x16x32_bf16(kf0, qf[qi][0], z4, 0, 0, 0);
                    s2[qi][kb] = __builtin_amdgcn_mfma_f32_16x16x32_bf16(kf1, qf[qi][1], t0, 0, 0, 0);
                }
            }
            __builtin_amdgcn_s_setprio(0);
            if (k0 + 63 > qw0) {
#pragma unroll
                for (int qi = 0; qi < 2; qi++)
#pragma unroll
                    for (int kb = 0; kb < 4; kb++)
#pragma unroll
                        for (int e = 0; e < 4; e++) {
                            const int kk = k0 + kb * 16 + g * 4 + e;
                            const int qq = qw0 + qi * 16 + l15;
                            if (kk > qq) s2[qi][kb][e] = NEG_INF;
                        }
            }
            // in-register online softmax, exp2 domain (q = l15 per lane)
#pragma unroll
            for (int qi = 0; qi < 2; qi++) {
                f32x4 mx = s2[qi][0];
#pragma unroll
                for (int kb = 1; kb < 4; kb++)
#pragma unroll
                    for (int e = 0; e < 4; e++) mx[e] = fmaxf(mx[e], s2[qi][kb][e]);
                float pmax = fmaxf(fmaxf(mx[0], mx[1]), fmaxf(mx[2], mx[3]));
                pmax = fmaxf(pmax, __shfl_xor(pmax, 16));
                pmax = fmaxf(pmax, __shfl_xor(pmax, 32));
                float mn = m[qi];
                const int resc = !__all(pmax <= mn + 11.541560f);   // defer-max (2^11.54 = e^8)
                if (resc) {
                    const float mold = mn;
                    mn = fmaxf(mold, pmax);
                    m[qi] = mn;
                    const float sc2 = ex2(mold - mn);
                    ls[qi] *= sc2;
#pragma unroll
                    for (int e = 0; e < 4; e++) {
                        const float sce = __shfl(sc2, (lane & 48) + (((lane >> 4) & 3) << 2) + e);
#pragma unroll
                        for (int n = 0; n < 4; n++) o_acc[qi][n][e] *= sce;
                    }
                }
                const int prow = qi * 16 + l15;
                u16* pb = &Plds[wv][prow * 64];
                float rsum = 0.f;
#pragma unroll
                for (int kb = 0; kb < 4; kb++) {
                    const float p0 = ex2(s2[qi][kb][0] - mn);
                    const float p1 = ex2(s2[qi][kb][1] - mn);
                    const float p2 = ex2(s2[qi][kb][2] - mn);
                    const float p3 = ex2(s2[qi][kb][3] - mn);
                    rsum += (p0 + p1) + (p2 + p3);
                    ushort4 pk;
                    pk.x = b16(p0); pk.y = b16(p1); pk.z = b16(p2); pk.w = b16(p3);
                    *(ushort4*)&pb[(((kb << 2) + g) ^ l15) * 4] = pk;
                }
                rsum += __shfl_xor(rsum, 16);
                rsum += __shfl_xor(rsum, 32);
                ls[qi] += rsum;
            }
            asm volatile("s_waitcnt lgkmcnt(0)" ::: "memory");
            // PV: A = P (row q=l15, keys g*8+j), B = V^T
            const int sw2 = l15 & 7;
#pragma unroll
            for (int ks = 0; ks < 2; ks++) {
                bf16x8 vf[4];
#pragma unroll
                for (int n = 0; n < 4; n++)
                    vf[n] = *(const bf16x8*)&Vlds[cur][(n * 16 + l15) * 64 + (((ks * 4 + g) ^ sw2) * 8)];
                __builtin_amdgcn_s_setprio(1);
#pragma unroll
                for (int qi = 0; qi < 2; qi++) {
                    const u16* pb = &Plds[wv][(qi * 16 + l15) * 64];
                    const int G0 = ((ks << 3) + (g << 1)) ^ l15;
                    const int G1 = ((ks << 3) + (g << 1) + 1) ^ l15;
                    const uint2 ra = *(const uint2*)&pb[G0 * 4];
                    const uint2 rb = *(const uint2*)&pb[G1 * 4];
                    union { uint32_t w[4]; bf16x8 v; } pu;
                    pu.w[0] = ra.x; pu.w[1] = ra.y; pu.w[2] = rb.x; pu.w[3] = rb.y;
#pragma unroll
                    for (int n = 0; n < 4; n++)
                        o_acc[qi][n] = __builtin_amdgcn_mfma_f32_16x16x32_bf16(pu.v, vf[n], o_acc[qi][n], 0, 0, 0);
                }
                __builtin_amdgcn_s_setprio(0);
            }
        }
        __builtin_amdgcn_s_barrier();
    }
#undef STAGE

    const int b = bh >> 4, h = bh & 15;
#pragma unroll
    for (int qi = 0; qi < 2; qi++) {
        const float linv = 1.f / ls[qi];
#pragma unroll
        for (int e = 0; e < 4; e++) {
            const float inv = __shfl(linv, (lane & 48) + (((lane >> 4) & 3) << 2) + e);
            const int t = qw0 + qi * 16 + g * 4 + e;
#pragma unroll
            for (int n = 0; n < 4; n++)
                o[((size_t)(b * TT + t)) * DD + h * HD + n * 16 + l15] = b16(o_acc[qi][n][e] * inv);
        }
    }
}

// ---------------- launch ----------------

extern "C" void kernel_launch(void* const* d_in, const int* in_sizes, int n_in,
                              void* d_out, int out_size, void* d_ws, size_t ws_size,
                              hipStream_t stream)
{
    const float* x     = (const float*)d_in[0];
    const float* w_qkv = (const float*)d_in[1];
    const float* w_o   = (const float*)d_in[2];
    float* out = (float*)d_out;
    char* ws = (char*)d_ws;

    u16* xb    = (u16*)(ws);                 // 8192x1024        16 MB
    u16* wqkvT = (u16*)(ws + 16777216);      // 3072x1024         6 MB
    u16* woT   = (u16*)(ws + 23068672);      // 1024x1024         2 MB
    u16* wsq   = (u16*)(ws + 25165824);      // [B,H,T,64]       16 MB
    u16* wsk   = (u16*)(ws + 41943040);      // [B,H,T,64]       16 MB
    u16* wsvT  = (u16*)(ws + 58720256);      // [B,H,64,T]       16 MB
    u16* attno = (u16*)(ws + 75497472);      // [B*T, D]         16 MB

    f32_to_bf16_vec<<<8192, 256, 0, stream>>>(x, xb, 2097152);
    dim3 tb(32, 8);
    transpose_f32_bf16<<<dim3(96, 32), tb, 0, stream>>>(w_qkv, wqkvT, 1024, 3072);
    transpose_f32_bf16<<<dim3(32, 32), tb, 0, stream>>>(w_o,   woT,   1024, 1024);

    gemm10<0><<<1536, 512, 0, stream>>>(xb, wqkvT, 3072, 1024, 1536, wsq, wsk, wsvT, nullptr);
    attn_fwd<<<1024, 256, 0, stream>>>(wsq, wsk, wsvT, attno);
    gemm10<1><<<512, 512, 0, stream>>>(attno, woT, 1024, 1024, 512, nullptr, nullptr, nullptr, out);
}